// Round 13
// baseline (2196.470 us; speedup 1.0000x reference)
//
#include <hip/hip_runtime.h>
#include <cstdint>
#include <cstddef>

#define H 450
#define H2 900
#define KP 480
#define KP2 960
#define NMESS 10241
#define NNODE 5120
#define MPAD 10368                 // 162 * 64
#define SPP1 960                   // packed row stride (shorts) for Kpad=480
#define SPP2 1920                  // for Kpad=960
#define PPSZ ((size_t)MPAD * SPP1) // packed plane size in shorts
#define KM 5
#define KN 6
#define LDCH 960                   // CHb/GU row stride (bf16)

typedef __attribute__((ext_vector_type(8))) short short8;   // 8 bf16
typedef __attribute__((ext_vector_type(4))) float f32x4;

__device__ __forceinline__ short bf16rne(float f) {
  union { float f; unsigned u; } x; x.f = f;
  unsigned u = x.u;
  u += 0x7FFF + ((u >> 16) & 1);
  return (short)(u >> 16);
}
__device__ __forceinline__ float bf16tof(short s) {
  union { float f; unsigned u; } x;
  x.u = ((unsigned)(unsigned short)s) << 16;
  return x.f;
}
__device__ __forceinline__ void bf16split(float v, short& hi, short& lo) {
  hi = bf16rne(v);
  lo = bf16rne(v - bf16tof(hi));
}
__device__ __forceinline__ float sigmoidf_(float x) {
  return 1.f / (1.f + __expf(-x));
}

// packed element offset: hi at PPIX, lo at PPIX+32
__device__ __forceinline__ size_t ppix(int row, int k, int spp) {
  return (size_t)row * spp + ((k >> 5) << 6) + (k & 31);
}

// ---------------- split-bf16 MFMA GEMM: DIRECT register loads ----------------
// A,B packed [row][k-chunk][hi*32|lo*32] bf16. 256 thr (4 waves, 32x32 wave
// tiles), no LDS, no barriers: per K-chunk each wave loads its fragments
// straight from global (L2-resident: B tiny, A panels XCD-swizzled).
// 2-deep register pipeline; lanes {l,l+16,l+32,l+48} coalesce to one 64B
// row segment per instruction.
#define BM 64
#define BN 64

__device__ __forceinline__ void xcd_swz(int gx, int gy, int& bm, int& bn) {
  const int nwg = gx * gy;
  int lid = blockIdx.y * gx + blockIdx.x;
  const int q = nwg >> 3, r = nwg & 7;
  const int xcd = lid & 7, seq = lid >> 3;
  int sid = (xcd < r) ? (xcd * (q + 1) + seq)
                      : (r * (q + 1) + (xcd - r) * q + seq);
  bm = (sid / gx) * BM;
  bn = (sid % gx) * BN;
}

struct Frag { short8 ah[2], al[2], bh[2], bl[2]; };

// OUT: 0 = f32 C (+bias, opt relu)
//      3 = single bf16 (Cs, stride ldc), +bias
//      4 = fused GRU combine: v = t_h; reads E1=CHb, E2=tzb, E3=shP;
//          writes h packed into Cs (ppix layout)
template<int ACT, int OUT>
__device__ __forceinline__ void gemm_core(
    const short* __restrict__ Apk, int Kpad,
    const short* __restrict__ Bpk,
    const float* __restrict__ bias,
    float* C, int ldc, short* Cs,
    const short* __restrict__ E1, const short* __restrict__ E2,
    const short* __restrict__ E3,
    int M, int N, int bm, int bn)
{
  const int tid  = threadIdx.x;
  const int lane = tid & 63;
  const int wid  = tid >> 6;          // 0..3
  const int wm   = (wid >> 1) * 32;
  const int wn   = (wid & 1) * 32;
  const int l15  = lane & 15;
  const int s8   = (lane >> 4) * 8;   // k sub-offset in halves
  const int rr0  = (lane >> 4) * 4;
  const int spp  = Kpad * 2;

  const short* pa0 = Apk + (size_t)(bm + wm +  0 + l15) * spp + s8;
  const short* pa1 = Apk + (size_t)(bm + wm + 16 + l15) * spp + s8;
  const short* pb0 = Bpk + (size_t)(bn + wn +  0 + l15) * spp + s8;
  const short* pb1 = Bpk + (size_t)(bn + wn + 16 + l15) * spp + s8;
  const int nk = Kpad / 32;

  f32x4 acc[2][2];
#pragma unroll
  for (int i = 0; i < 2; ++i)
#pragma unroll
    for (int j = 0; j < 2; ++j)
#pragma unroll
      for (int t = 0; t < 4; ++t) acc[i][j][t] = 0.f;

  Frag f0, f1;
  auto LOADF = [&](Frag& f, int t) {
    const int o = t * 64;
    f.ah[0] = *(const short8*)(pa0 + o); f.al[0] = *(const short8*)(pa0 + o + 32);
    f.ah[1] = *(const short8*)(pa1 + o); f.al[1] = *(const short8*)(pa1 + o + 32);
    f.bh[0] = *(const short8*)(pb0 + o); f.bl[0] = *(const short8*)(pb0 + o + 32);
    f.bh[1] = *(const short8*)(pb1 + o); f.bl[1] = *(const short8*)(pb1 + o + 32);
  };
  auto MF = [&](Frag& f) {
    __builtin_amdgcn_s_setprio(1);
#pragma unroll
    for (int j = 0; j < 2; ++j)
#pragma unroll
      for (int i = 0; i < 2; ++i) {
        acc[i][j] = __builtin_amdgcn_mfma_f32_16x16x32_bf16(f.ah[i], f.bh[j], acc[i][j], 0, 0, 0);
        acc[i][j] = __builtin_amdgcn_mfma_f32_16x16x32_bf16(f.al[i], f.bh[j], acc[i][j], 0, 0, 0);
        acc[i][j] = __builtin_amdgcn_mfma_f32_16x16x32_bf16(f.ah[i], f.bl[j], acc[i][j], 0, 0, 0);
      }
    __builtin_amdgcn_s_setprio(0);
  };

  LOADF(f0, 0);
  int t = 0;
  for (; t + 1 < nk; t += 2) {
    LOADF(f1, t + 1);
    MF(f0);
    if (t + 2 < nk) LOADF(f0, t + 2);
    MF(f1);
  }
  if (t < nk) MF(f0);   // nk odd tail (f0 pre-loaded)

#pragma unroll
  for (int j = 0; j < 2; ++j) {
    int col = bn + wn + j*16 + l15;
    if (col >= N) continue;
    float bv = ((OUT == 0 || OUT == 3) && bias) ? bias[col] : 0.f;
#pragma unroll
    for (int i = 0; i < 2; ++i) {
      int row0 = bm + wm + i*16 + rr0;
#pragma unroll
      for (int rr = 0; rr < 4; ++rr) {
        int row = row0 + rr;
        if (row >= M) continue;
        float v = acc[i][j][rr] + bv;
        if (OUT == 0) {
          if (ACT == 1) v = fmaxf(v, 0.f);
          C[(size_t)row * ldc + col] = v;
        } else if (OUT == 3) {
          Cs[(size_t)row * ldc + col] = bf16rne(v);
        } else {  // OUT == 4: fused combine; v = t_h
          float tz = bf16tof(E2[(size_t)row * 480 + col]);
          float cz = bf16tof(E1[(size_t)row * LDCH + col]);
          float ch = bf16tof(E1[(size_t)row * LDCH + 450 + col]);
          size_t op = ppix(row, col, SPP1);
          float sm2 = bf16tof(E3[op]) + bf16tof(E3[op + 32]);
          float z   = sigmoidf_(cz + tz);
          float pre = tanhf(ch + v);
          float hv  = (1.f - z) * sm2 + z * pre;
          if (row == 0) hv = 0.f;
          short hi, lo; bf16split(hv, hi, lo);
          Cs[op] = hi; Cs[op + 32] = lo;
        }
      }
    }
  }
}

template<int ACT>
__global__ __launch_bounds__(256, 4)
void gemm4(const short* __restrict__ Apk, int Kpad,
           const short* __restrict__ Bpk,
           const float* __restrict__ bias,
           float* C, int ldc, int M, int N)
{
  int bm, bn; xcd_swz(gridDim.x, gridDim.y, bm, bn);
  gemm_core<ACT, 0>(Apk, Kpad, Bpk, bias, C, ldc, nullptr,
                    nullptr, nullptr, nullptr, M, N, bm, bn);
}

// single-bf16 output GEMM (CHb, r1b, GU)
__global__ __launch_bounds__(256, 4)
void gemm4_b(const short* __restrict__ Apk, int Kpad,
             const short* __restrict__ Bpk,
             const float* __restrict__ bias,
             short* Cs, int ldcs, int M, int N)
{
  int bm, bn; xcd_swz(gridDim.x, gridDim.y, bm, bn);
  gemm_core<0, 3>(Apk, Kpad, Bpk, bias, nullptr, ldcs, Cs,
                  nullptr, nullptr, nullptr, M, N, bm, bn);
}

// t_h GEMM with fused GRU combine: h = mask*((1-z)*sum_h + z*tanh(c_h+t_h))
__global__ __launch_bounds__(256, 4)
void gemm4_thc(const short* __restrict__ Apk,
               const short* __restrict__ Bpk,
               const short* __restrict__ CHb,
               const short* __restrict__ tzb,
               const short* __restrict__ shP,
               short* hP)
{
  int bm, bn; xcd_swz(gridDim.x, gridDim.y, bm, bn);
  gemm_core<0, 4>(Apk, KP, Bpk, nullptr, nullptr, 0, hP,
                  CHb, tzb, shP, NMESS, H, bm, bn);
}

// ---------------- weight transpose + packed bf16 hi/lo split ----------------
// Bt packed [c][chunk][hi|lo], c = column of original W; c < rmax written
__global__ __launch_bounds__(256)
void k_wT(const float* __restrict__ W, int Kreal,
          short* __restrict__ Bt, int Kpad, int rmax) {
  __shared__ float T[32][33];
  const int tx = threadIdx.x & 31;
  const int ty = threadIdx.x >> 5;
  const int k0 = blockIdx.x * 32;
  const int c0 = blockIdx.y * 32;
  const int spp = Kpad * 2;
#pragma unroll
  for (int i = 0; i < 4; ++i) {
    int k = k0 + ty + i*8, c = c0 + tx;
    T[ty + i*8][tx] = (k < Kreal && c < H) ? W[(size_t)k * H + c] : 0.f;
  }
  __syncthreads();
#pragma unroll
  for (int i = 0; i < 4; ++i) {
    int c = c0 + ty + i*8, k = k0 + tx;
    if (k < Kpad && c < rmax) {
      short hi, lo;
      bf16split(T[tx][ty + i*8], hi, lo);
      size_t o = ppix(c, k, spp);
      Bt[o] = hi; Bt[o + 32] = lo;
    }
  }
}

__global__ void k_biascat(const float* __restrict__ bz, const float* __restrict__ bh,
                          float* __restrict__ biasI) {
  int c = blockIdx.x * blockDim.x + threadIdx.x;
  if (c >= 900) return;
  biasI[c] = (c < 450) ? bz[c] : bh[c - 450];
}

// ---------------- elementwise / gather kernels ----------------

__global__ void k_build_idx(const int* __restrict__ fnode,
                            const int* __restrict__ fmess,
                            int* __restrict__ idxM) {
  int m = blockIdx.x * blockDim.x + threadIdx.x;
  if (m < NMESS) idxM[m] = fnode[fmess[m]];
}

__global__ void k_embsplit(const float* __restrict__ emb,
                           const int* __restrict__ idxM,
                           short* __restrict__ eP) {
  int m = blockIdx.x, j = threadIdx.x * 2;
  if (j >= KP) return;
  size_t o = ppix(m, j, SPP1);
  if (j < H) {
    float2 v = *(const float2*)&emb[(size_t)idxM[m] * H + j];
    short2 h2, l2;
    bf16split(v.x, h2.x, l2.x); bf16split(v.y, h2.y, l2.y);
    *(short2*)&eP[o] = h2; *(short2*)&eP[o + 32] = l2;
  } else {                      // K-tail cols [450,480) must be 0
    short2 z2; z2.x = 0; z2.y = 0;
    *(short2*)&eP[o] = z2; *(short2*)&eP[o + 32] = z2;
  }
}

// step 0: h1 = mask * sigmoid(c_z) * tanh(c_h)   (sum_h = t_z = t_h = 0)
__global__ void k_h1(const short* __restrict__ CHb, short* __restrict__ hP) {
  int m = blockIdx.x, j = threadIdx.x * 2;
  if (j >= KP) return;
  size_t oP = ppix(m, j, SPP1);
  if (j < H) {
    size_t oc = (size_t)m * LDCH + j;
    short2 cz2 = *(const short2*)&CHb[oc];
    short2 ch2 = *(const short2*)&CHb[oc + 450];
    float v0 = sigmoidf_(bf16tof(cz2.x)) * tanhf(bf16tof(ch2.x));
    float v1 = sigmoidf_(bf16tof(cz2.y)) * tanhf(bf16tof(ch2.y));
    if (m == 0) { v0 = 0.f; v1 = 0.f; }
    short2 h2, l2;
    bf16split(v0, h2.x, l2.x); bf16split(v1, h2.y, l2.y);
    *(short2*)&hP[oP] = h2; *(short2*)&hP[oP + 32] = l2;
  } else {
    short2 z2; z2.x = 0; z2.y = 0;
    *(short2*)&hP[oP] = z2; *(short2*)&hP[oP + 32] = z2;
  }
}

// one pass over neighbors: sum_h (packed), sum_gh (packed), t_z = sum u[e] (bf16)
// GU[e] = [g | u] bf16, stride 960: g = h@Ur (cols 0-449), u = h@WzB (cols 450-899)
__global__ void k_gather3(const short* __restrict__ hP,
                          const short* __restrict__ GU,
                          const short* __restrict__ r1b,   // [M][480] bf16
                          const int* __restrict__ mg,
                          short* __restrict__ shP, short* __restrict__ ghP,
                          short* __restrict__ tzb) {
  int m = blockIdx.x, j = threadIdx.x * 2;
  if (j >= KP) return;
  size_t o = ppix(m, j, SPP1);
  if (j >= H) {                 // K-tail zeros
    short2 z2; z2.x = 0; z2.y = 0;
    *(short2*)&shP[o] = z2; *(short2*)&shP[o + 32] = z2;
    *(short2*)&ghP[o] = z2; *(short2*)&ghP[o + 32] = z2;
    return;
  }
  const int* e = mg + (size_t)m * KM;
  short2 rb2 = *(const short2*)&r1b[(size_t)m * 480 + j];
  float rb0 = bf16tof(rb2.x), rb1 = bf16tof(rb2.y);
  float s0 = 0.f, s1 = 0.f, t0 = 0.f, t1 = 0.f, u0 = 0.f, u1 = 0.f;
#pragma unroll
  for (int k = 0; k < KM; ++k) {
    int ek = e[k];
    size_t oP = ppix(ek, j, SPP1);
    size_t oG = (size_t)ek * LDCH + j;
    short2 gv = *(const short2*)&GU[oG];
    short2 uv = *(const short2*)&GU[oG + 450];
    short2 ph = *(const short2*)&hP[oP];
    short2 pl = *(const short2*)&hP[oP + 32];
    float h0 = bf16tof(ph.x) + bf16tof(pl.x);
    float h1 = bf16tof(ph.y) + bf16tof(pl.y);
    s0 += h0;                                  s1 += h1;
    t0 += sigmoidf_(rb0 + bf16tof(gv.x)) * h0; t1 += sigmoidf_(rb1 + bf16tof(gv.y)) * h1;
    u0 += bf16tof(uv.x);                       u1 += bf16tof(uv.y);
  }
  short2 h2, l2;
  bf16split(s0, h2.x, l2.x); bf16split(s1, h2.y, l2.y);
  *(short2*)&shP[o] = h2; *(short2*)&shP[o + 32] = l2;
  bf16split(t0, h2.x, l2.x); bf16split(t1, h2.y, l2.y);
  *(short2*)&ghP[o] = h2; *(short2*)&ghP[o + 32] = l2;
  short2 tz2; tz2.x = bf16rne(u0); tz2.y = bf16rne(u1);
  *(short2*)&tzb[(size_t)m * 480 + j] = tz2;
}

// Acat packed [n][SPP2]: cols 0-449 = emb, 450-899 = sum h_nei, 900-959 = 0
__global__ void k_nodecat(const float* __restrict__ emb,
                          const int* __restrict__ fnode,
                          const short* __restrict__ hP,
                          const int* __restrict__ ng,
                          short* __restrict__ Apk) {
  int n = blockIdx.x, t = threadIdx.x, j = t * 2;
  if (j < H) {
    float2 v = *(const float2*)&emb[(size_t)fnode[n] * H + j];
    short2 h2, l2;
    bf16split(v.x, h2.x, l2.x); bf16split(v.y, h2.y, l2.y);
    size_t o = ppix(n, j, SPP2);
    *(short2*)&Apk[o] = h2; *(short2*)&Apk[o + 32] = l2;

    const int* e = ng + (size_t)n * KN;
    float s0 = 0.f, s1 = 0.f;
#pragma unroll
    for (int k = 0; k < KN; ++k) {
      size_t oP = ppix(e[k], j, SPP1);
      short2 ph = *(const short2*)&hP[oP];
      short2 pl = *(const short2*)&hP[oP + 32];
      s0 += bf16tof(ph.x) + bf16tof(pl.x);
      s1 += bf16tof(ph.y) + bf16tof(pl.y);
    }
    bf16split(s0, h2.x, l2.x); bf16split(s1, h2.y, l2.y);
    o = ppix(n, 450 + j, SPP2);
    *(short2*)&Apk[o] = h2; *(short2*)&Apk[o + 32] = l2;
  }
  if (t < 30) {   // zero cols [900,960)
    int c = 900 + t * 2;
    short2 z2; z2.x = 0; z2.y = 0;
    size_t o = ppix(n, c, SPP2);
    *(short2*)&Apk[o] = z2; *(short2*)&Apk[o + 32] = z2;
  }
}

// ---------------- launch ----------------

extern "C" void kernel_launch(void* const* d_in, const int* in_sizes, int n_in,
                              void* d_out, int out_size, void* d_ws, size_t ws_size,
                              hipStream_t stream) {
  (void)in_sizes; (void)n_in; (void)out_size; (void)ws_size;

  const int*   fnode      = (const int*)d_in[0];
  const int*   fmess      = (const int*)d_in[1];
  const int*   node_graph = (const int*)d_in[2];
  const int*   mess_graph = (const int*)d_in[3];
  const float* emb        = (const float*)d_in[4];
  const float* Wz         = (const float*)d_in[5];
  const float* bz         = (const float*)d_in[6];
  const float* Wr         = (const float*)d_in[7];
  const float* Ur         = (const float*)d_in[8];
  const float* bu         = (const float*)d_in[9];
  const float* Wh         = (const float*)d_in[10];
  const float* bh         = (const float*)d_in[11];
  const float* Wo         = (const float*)d_in[12];
  const float* bo         = (const float*)d_in[13];

  // ---- workspace: 3 packed planes + CHb + GU + r1b + tzb ≈ 118.7 MB ----
  short* P   = (short*)d_ws;
  short* hP  = P;                     // h packed
  short* shP = P + 1 * PPSZ;          // sum_h packed (later Acat @ SPP2)
  short* ghP = P + 2 * PPSZ;          // sum_gh packed (also fmess_e packed)
  short* CHb = P + 3 * PPSZ;                       // [M][960] bf16: c_z | c_h
  short* GU  = CHb + (size_t)NMESS * LDCH;         // [M][960] bf16: g | u
  short* r1b = GU  + (size_t)NMESS * LDCH;         // [M][480] bf16
  short* tzb = r1b + (size_t)NMESS * 480;          // [M][480] bf16

  // ---- d_out messages region: packed weights (~8.7 of 18.4 MB) ----
  char*  scr  = (char*)d_out + (size_t)NNODE * H * 4;   // 16B-aligned
  short* BtI  = (short*)scr;                    // [1408][960] packed (WzT|WhT)
  short* BtR  = BtI  + (size_t)1408 * SPP1;     // [512][960] Wr
  short* BtGU = BtR  + (size_t)512 * SPP1;      // [1024][960]: Ur rows 0-449, WzB rows 450-899
  short* BtHH = BtGU + (size_t)1024 * SPP1;     // [512][960] Wh bottom
  short* BtO  = BtHH + (size_t)512 * SPP1;      // [512][1920] Wo
  float* biasI = (float*)(BtO + (size_t)512 * SPP2);    // [900]
  int*   idxM  = (int*)(biasI + 912);

  k_build_idx<<<(NMESS + 255) / 256, 256, 0, stream>>>(fnode, fmess, idxM);

  // packed weight prep (fully overwrites every region read later)
  dim3 gT(KP / 32, 16), gT2(KP2 / 32, 16);
  k_wT<<<gT,  256, 0, stream>>>(Wz,                  H, BtI,               KP,  512);
  k_wT<<<gT,  256, 0, stream>>>(Wh,                  H, BtI + 450 * SPP1,  KP,  512);
  k_wT<<<gT,  256, 0, stream>>>(Wr,                  H, BtR,               KP,  512);
  k_wT<<<gT,  256, 0, stream>>>(Ur,                  H, BtGU,              KP,  512);
  k_wT<<<gT,  256, 0, stream>>>(Wz + (size_t)H * H,  H, BtGU + 450 * SPP1, KP,  512);
  k_wT<<<gT,  256, 0, stream>>>(Wh + (size_t)H * H,  H, BtHH,              KP,  512);
  k_wT<<<gT2, 256, 0, stream>>>(Wo,                 H2, BtO,               KP2, 512);
  k_biascat<<<4, 256, 0, stream>>>(bz, bh, biasI);

  // fmess_e packed into ghP (writes K-tail zeros inline)
  k_embsplit<<<NMESS, 256, 0, stream>>>(emb, idxM, ghP);

  // invariant GEMMs: CHb (c_z|c_h, bf16) and r1b (bf16)
  dim3 gI1(15, MPAD / BM);   // N=900
  gemm4_b<<<gI1, 256, 0, stream>>>(ghP, KP, BtI, biasI, CHb, LDCH, NMESS, H2);
  dim3 gI2(8, MPAD / BM);    // N=450
  gemm4_b<<<gI2, 256, 0, stream>>>(ghP, KP, BtR, bu, r1b, 480, NMESS, H);

  // step 0 shortcut: h1 = mask * sigmoid(c_z) * tanh(c_h)
  k_h1<<<NMESS, 256, 0, stream>>>(CHb, hP);

  dim3 gGU(15, MPAD / BM);   // N=900: [g|u] = h @ [Ur|WzB]
  dim3 gB(8, MPAD / BM);     // N=450: t_h (+fused combine)
  for (int d = 1; d < 8; ++d) {
    gemm4_b<<<gGU, 256, 0, stream>>>(hP, KP, BtGU, nullptr, GU, LDCH, NMESS, H2);
    k_gather3<<<NMESS, 256, 0, stream>>>(hP, GU, r1b, mess_graph, shP, ghP, tzb);
    gemm4_thc<<<gB, 256, 0, stream>>>(ghP, BtHH, CHb, tzb, shP, hP);
  }

  // Acat packed (SPP2) then output GEMM with relu
  k_nodecat<<<NNODE, 256, 0, stream>>>(emb, fnode, hP, node_graph, shP);
  dim3 gF(8, NNODE / BM);    // (8, 80)
  gemm4<1><<<gF, 256, 0, stream>>>(shP, KP2, BtO, bo, (float*)d_out, H, NNODE, H);

  // messages output = zeros (wipes idx + weights) — AFTER final GEMM
  hipMemsetAsync((float*)d_out + (size_t)NNODE * H, 0, (size_t)NMESS * H * sizeof(float), stream);
}

// Round 14
// 922.066 us; speedup vs baseline: 2.3821x; 2.3821x over previous
//
#include <hip/hip_runtime.h>
#include <cstdint>
#include <cstddef>

#define H 450
#define H2 900
#define KP 480
#define KP2 960
#define NMESS 10241
#define NNODE 5120
#define MPAD 10368                 // 162 * 64
#define SPP1 960                   // packed row stride (shorts) for Kpad=480
#define SPP2 1920                  // for Kpad=960
#define PPSZ ((size_t)MPAD * SPP1) // packed plane size in shorts
#define KM 5
#define KN 6
#define LDCH 960                   // CHb/GU row stride (bf16)

typedef __attribute__((ext_vector_type(8))) short short8;   // 8 bf16
typedef __attribute__((ext_vector_type(4))) float f32x4;

__device__ __forceinline__ short bf16rne(float f) {
  union { float f; unsigned u; } x; x.f = f;
  unsigned u = x.u;
  u += 0x7FFF + ((u >> 16) & 1);
  return (short)(u >> 16);
}
__device__ __forceinline__ float bf16tof(short s) {
  union { float f; unsigned u; } x;
  x.u = ((unsigned)(unsigned short)s) << 16;
  return x.f;
}
__device__ __forceinline__ void bf16split(float v, short& hi, short& lo) {
  hi = bf16rne(v);
  lo = bf16rne(v - bf16tof(hi));
}
__device__ __forceinline__ float sigmoidf_(float x) {
  return 1.f / (1.f + __expf(-x));
}

// packed element offset: hi at PPIX, lo at PPIX+32
__device__ __forceinline__ size_t ppix(int row, int k, int spp) {
  return (size_t)row * spp + ((k >> 5) << 6) + (k & 31);
}

// direct global->LDS 16B DMA (LDS dest: wave-uniform base + lane*16)
__device__ __forceinline__ void gll16(const short* g, short* l) {
  __builtin_amdgcn_global_load_lds(
      (const __attribute__((address_space(1))) void*)g,
      (__attribute__((address_space(3))) void*)l, 16, 0, 0);
}

// ---------------- split-bf16 MFMA GEMM: packed planes (r11-proven core) ----
// A,B packed [row][k-chunk][hi*32|lo*32] bf16. 256 thr (4 waves, 32x32 wave
// tiles), BK=32, 2-buf 32 KB LDS -> 5 blocks/CU. gload_lds staging: one
// contiguous 128B run per row per chunk; source slot = (lane&7)^(row&7),
// read-side XOR matches. XCD-chunked block swizzle.
#define BM 64
#define BN 64
#define BK 32

struct SmemT { short As[2][64][64]; short Bs[2][64][64]; };   // 32 KB

__device__ __forceinline__ void xcd_swz(int gx, int gy, int& bm, int& bn) {
  const int nwg = gx * gy;
  int lid = blockIdx.y * gx + blockIdx.x;
  const int q = nwg >> 3, r = nwg & 7;
  const int xcd = lid & 7, seq = lid >> 3;
  int sid = (xcd < r) ? (xcd * (q + 1) + seq)
                      : (r * (q + 1) + (xcd - r) * q + seq);
  bm = (sid / gx) * BM;
  bn = (sid % gx) * BN;
}

// OUT: 0 = f32 C (+bias, opt relu)
//      3 = single bf16 (Cs, stride ldc), +bias
template<int ACT, int OUT>
__device__ __forceinline__ void gemm_core(
    SmemT& sm, const short* __restrict__ Apk, int Kpad,
    const short* __restrict__ Bpk,
    const float* __restrict__ bias,
    float* C, int ldc, short* Cs,
    int M, int N, int bm, int bn)
{
  const int tid  = threadIdx.x;
  const int lane = tid & 63;
  const int wid  = tid >> 6;          // 0..3
  const int wm   = (wid >> 1) * 32;
  const int wn   = (wid & 1) * 32;
  const int l15  = lane & 15;
  const int s8   = (lane >> 4) * 8;   // k sub-offset in halves
  const int rr0  = (lane >> 4) * 4;
  const int spp  = Kpad * 2;

  // staging: unified 128 rows (0-63 = A, 64-127 = B); wave wid -> rows 32w..32w+31
  const int lr = lane >> 3;
  const int sl = lane & 7;
  const int t0 = sl ^ lr;             // packed slot (0-3 hi, 4-7 lo)
  const short* src[4];
#pragma unroll
  for (int qq = 0; qq < 4; ++qq) {
    const int rrow = wid * 32 + qq * 8 + lr;
    const bool isA = rrow < 64;
    const int grow = isA ? (bm + rrow) : (bn + rrow - 64);
    src[qq] = (isA ? Apk : Bpk) + (size_t)grow * spp + t0 * 8;
  }
  const int nk = Kpad / BK;

  f32x4 acc[2][2];
#pragma unroll
  for (int i = 0; i < 2; ++i)
#pragma unroll
    for (int j = 0; j < 2; ++j)
#pragma unroll
      for (int t = 0; t < 4; ++t) acc[i][j][t] = 0.f;

  auto STAGE = [&](int b, int koff) {
#pragma unroll
    for (int qq = 0; qq < 4; ++qq) {
      const int r0 = wid * 32 + qq * 8;
      short* d = (r0 < 64) ? &sm.As[b][r0][0] : &sm.Bs[b][r0 - 64][0];
      gll16(src[qq] + koff, d);
    }
  };

  STAGE(0, 0);
  __syncthreads();
  int cur = 0;
  for (int t = 0; t < nk; ++t) {
    if (t + 1 < nk) STAGE(cur ^ 1, (t + 1) * 64);
    short8 ah[2], al[2], bh[2], bl[2];
#pragma unroll
    for (int i = 0; i < 2; ++i) {
      const int rA = wm + i*16 + l15;
      const int xr = (rA & 7) << 3;
      ah[i] = *(const short8*)&sm.As[cur][rA][(s8)      ^ xr];
      al[i] = *(const short8*)&sm.As[cur][rA][(s8 + 32) ^ xr];
    }
#pragma unroll
    for (int j = 0; j < 2; ++j) {
      const int rB = wn + j*16 + l15;
      const int xr = (rB & 7) << 3;
      bh[j] = *(const short8*)&sm.Bs[cur][rB][(s8)      ^ xr];
      bl[j] = *(const short8*)&sm.Bs[cur][rB][(s8 + 32) ^ xr];
    }
    __builtin_amdgcn_s_setprio(1);
#pragma unroll
    for (int j = 0; j < 2; ++j)
#pragma unroll
      for (int i = 0; i < 2; ++i) {
        acc[i][j] = __builtin_amdgcn_mfma_f32_16x16x32_bf16(ah[i], bh[j], acc[i][j], 0, 0, 0);
        acc[i][j] = __builtin_amdgcn_mfma_f32_16x16x32_bf16(al[i], bh[j], acc[i][j], 0, 0, 0);
        acc[i][j] = __builtin_amdgcn_mfma_f32_16x16x32_bf16(ah[i], bl[j], acc[i][j], 0, 0, 0);
      }
    __builtin_amdgcn_s_setprio(0);
    __syncthreads();   // drains next-tile gload_lds + read/write order
    cur ^= 1;
  }

#pragma unroll
  for (int j = 0; j < 2; ++j) {
    int col = bn + wn + j*16 + l15;
    if (col >= N) continue;
    float bv = bias ? bias[col] : 0.f;
#pragma unroll
    for (int i = 0; i < 2; ++i) {
      int row0 = bm + wm + i*16 + rr0;
#pragma unroll
      for (int rr = 0; rr < 4; ++rr) {
        int row = row0 + rr;
        if (row >= M) continue;
        float v = acc[i][j][rr] + bv;
        if (OUT == 0) {
          if (ACT == 1) v = fmaxf(v, 0.f);
          C[(size_t)row * ldc + col] = v;
        } else {  // OUT == 3: single bf16, stride ldc
          Cs[(size_t)row * ldc + col] = bf16rne(v);
        }
      }
    }
  }
}

template<int ACT>
__global__ __launch_bounds__(256, 5)
void gemm4(const short* __restrict__ Apk, int Kpad,
           const short* __restrict__ Bpk,
           const float* __restrict__ bias,
           float* C, int ldc, int M, int N)
{
  __shared__ SmemT sm;
  int bm, bn; xcd_swz(gridDim.x, gridDim.y, bm, bn);
  gemm_core<ACT, 0>(sm, Apk, Kpad, Bpk, bias, C, ldc, nullptr, M, N, bm, bn);
}

// single-bf16 output GEMM (CHb, r1b, GU, thb)
__global__ __launch_bounds__(256, 5)
void gemm4_b(const short* __restrict__ Apk, int Kpad,
             const short* __restrict__ Bpk,
             const float* __restrict__ bias,
             short* Cs, int ldcs, int M, int N)
{
  __shared__ SmemT sm;
  int bm, bn; xcd_swz(gridDim.x, gridDim.y, bm, bn);
  gemm_core<0, 3>(sm, Apk, Kpad, Bpk, bias, nullptr, ldcs, Cs, M, N, bm, bn);
}

// ---------------- weight transpose + packed bf16 hi/lo split ----------------
// Bt packed [c][chunk][hi|lo], c = column of original W; c < rmax written
__global__ __launch_bounds__(256)
void k_wT(const float* __restrict__ W, int Kreal,
          short* __restrict__ Bt, int Kpad, int rmax) {
  __shared__ float T[32][33];
  const int tx = threadIdx.x & 31;
  const int ty = threadIdx.x >> 5;
  const int k0 = blockIdx.x * 32;
  const int c0 = blockIdx.y * 32;
  const int spp = Kpad * 2;
#pragma unroll
  for (int i = 0; i < 4; ++i) {
    int k = k0 + ty + i*8, c = c0 + tx;
    T[ty + i*8][tx] = (k < Kreal && c < H) ? W[(size_t)k * H + c] : 0.f;
  }
  __syncthreads();
#pragma unroll
  for (int i = 0; i < 4; ++i) {
    int c = c0 + ty + i*8, k = k0 + tx;
    if (k < Kpad && c < rmax) {
      short hi, lo;
      bf16split(T[tx][ty + i*8], hi, lo);
      size_t o = ppix(c, k, spp);
      Bt[o] = hi; Bt[o + 32] = lo;
    }
  }
}

__global__ void k_biascat(const float* __restrict__ bz, const float* __restrict__ bh,
                          float* __restrict__ biasI) {
  int c = blockIdx.x * blockDim.x + threadIdx.x;
  if (c >= 900) return;
  biasI[c] = (c < 450) ? bz[c] : bh[c - 450];
}

// ---------------- elementwise / gather kernels ----------------

__global__ void k_build_idx(const int* __restrict__ fnode,
                            const int* __restrict__ fmess,
                            int* __restrict__ idxM) {
  int m = blockIdx.x * blockDim.x + threadIdx.x;
  if (m < NMESS) idxM[m] = fnode[fmess[m]];
}

__global__ void k_embsplit(const float* __restrict__ emb,
                           const int* __restrict__ idxM,
                           short* __restrict__ eP) {
  int m = blockIdx.x, j = threadIdx.x * 2;
  if (j >= KP) return;
  size_t o = ppix(m, j, SPP1);
  if (j < H) {
    float2 v = *(const float2*)&emb[(size_t)idxM[m] * H + j];
    short2 h2, l2;
    bf16split(v.x, h2.x, l2.x); bf16split(v.y, h2.y, l2.y);
    *(short2*)&eP[o] = h2; *(short2*)&eP[o + 32] = l2;
  } else {                      // K-tail cols [450,480) must be 0
    short2 z2; z2.x = 0; z2.y = 0;
    *(short2*)&eP[o] = z2; *(short2*)&eP[o + 32] = z2;
  }
}

// step 0: h1 = mask * sigmoid(c_z) * tanh(c_h)   (sum_h = t_z = t_h = 0)
__global__ void k_h1(const short* __restrict__ CHb, short* __restrict__ hP) {
  int m = blockIdx.x, j = threadIdx.x * 2;
  if (j >= KP) return;
  size_t oP = ppix(m, j, SPP1);
  if (j < H) {
    size_t oc = (size_t)m * LDCH + j;
    short2 cz2 = *(const short2*)&CHb[oc];
    short2 ch2 = *(const short2*)&CHb[oc + 450];
    float v0 = sigmoidf_(bf16tof(cz2.x)) * tanhf(bf16tof(ch2.x));
    float v1 = sigmoidf_(bf16tof(cz2.y)) * tanhf(bf16tof(ch2.y));
    if (m == 0) { v0 = 0.f; v1 = 0.f; }
    short2 h2, l2;
    bf16split(v0, h2.x, l2.x); bf16split(v1, h2.y, l2.y);
    *(short2*)&hP[oP] = h2; *(short2*)&hP[oP + 32] = l2;
  } else {
    short2 z2; z2.x = 0; z2.y = 0;
    *(short2*)&hP[oP] = z2; *(short2*)&hP[oP + 32] = z2;
  }
}

// one pass over neighbors: sum_h (packed), sum_gh (packed), t_z = sum u[e] (bf16)
// GU[e] = [g | u] bf16, stride 960: g = h@Ur (cols 0-449), u = h@WzB (cols 450-899)
__global__ void k_gather3(const short* __restrict__ hP,
                          const short* __restrict__ GU,
                          const short* __restrict__ r1b,   // [M][480] bf16
                          const int* __restrict__ mg,
                          short* __restrict__ shP, short* __restrict__ ghP,
                          short* __restrict__ tzb) {
  int m = blockIdx.x, j = threadIdx.x * 2;
  if (j >= KP) return;
  size_t o = ppix(m, j, SPP1);
  if (j >= H) {                 // K-tail zeros
    short2 z2; z2.x = 0; z2.y = 0;
    *(short2*)&shP[o] = z2; *(short2*)&shP[o + 32] = z2;
    *(short2*)&ghP[o] = z2; *(short2*)&ghP[o + 32] = z2;
    return;
  }
  const int* e = mg + (size_t)m * KM;
  short2 rb2 = *(const short2*)&r1b[(size_t)m * 480 + j];
  float rb0 = bf16tof(rb2.x), rb1 = bf16tof(rb2.y);
  float s0 = 0.f, s1 = 0.f, t0 = 0.f, t1 = 0.f, u0 = 0.f, u1 = 0.f;
#pragma unroll
  for (int k = 0; k < KM; ++k) {
    int ek = e[k];
    size_t oP = ppix(ek, j, SPP1);
    size_t oG = (size_t)ek * LDCH + j;
    short2 gv = *(const short2*)&GU[oG];
    short2 uv = *(const short2*)&GU[oG + 450];
    short2 ph = *(const short2*)&hP[oP];
    short2 pl = *(const short2*)&hP[oP + 32];
    float h0 = bf16tof(ph.x) + bf16tof(pl.x);
    float h1 = bf16tof(ph.y) + bf16tof(pl.y);
    s0 += h0;                                  s1 += h1;
    t0 += sigmoidf_(rb0 + bf16tof(gv.x)) * h0; t1 += sigmoidf_(rb1 + bf16tof(gv.y)) * h1;
    u0 += bf16tof(uv.x);                       u1 += bf16tof(uv.y);
  }
  short2 h2, l2;
  bf16split(s0, h2.x, l2.x); bf16split(s1, h2.y, l2.y);
  *(short2*)&shP[o] = h2; *(short2*)&shP[o + 32] = l2;
  bf16split(t0, h2.x, l2.x); bf16split(t1, h2.y, l2.y);
  *(short2*)&ghP[o] = h2; *(short2*)&ghP[o + 32] = l2;
  short2 tz2; tz2.x = bf16rne(u0); tz2.y = bf16rne(u1);
  *(short2*)&tzb[(size_t)m * 480 + j] = tz2;
}

// h = mask*((1-z)*sum_h + z*tanh(c_h+t_h)); coalesced, in place on hP
__global__ void k_combine(const short* __restrict__ CHb,   // [M][960] bf16: c_z|c_h
                          const short* __restrict__ tzb,   // [M][480] bf16
                          const short* __restrict__ thb,   // [M][480] bf16
                          const short* __restrict__ shP,
                          short* hP) {
  int m = blockIdx.x, j = threadIdx.x * 2;
  if (j >= H) return;           // K-tail of hP stays zero (only h1/combine write hP)
  size_t oc = (size_t)m * LDCH + j;
  size_t oP = ppix(m, j, SPP1);
  short2 cz2 = *(const short2*)&CHb[oc];
  short2 ch2 = *(const short2*)&CHb[oc + 450];
  short2 tz2 = *(const short2*)&tzb[(size_t)m * 480 + j];
  short2 th2 = *(const short2*)&thb[(size_t)m * 480 + j];
  short2 smh = *(const short2*)&shP[oP];
  short2 sml = *(const short2*)&shP[oP + 32];
  float sm0 = bf16tof(smh.x) + bf16tof(sml.x);
  float sm1 = bf16tof(smh.y) + bf16tof(sml.y);
  float z0 = sigmoidf_(bf16tof(cz2.x) + bf16tof(tz2.x));
  float z1 = sigmoidf_(bf16tof(cz2.y) + bf16tof(tz2.y));
  float p0 = tanhf(bf16tof(ch2.x) + bf16tof(th2.x));
  float p1 = tanhf(bf16tof(ch2.y) + bf16tof(th2.y));
  float v0 = (1.f - z0) * sm0 + z0 * p0;
  float v1 = (1.f - z1) * sm1 + z1 * p1;
  if (m == 0) { v0 = 0.f; v1 = 0.f; }
  short2 h2, l2;
  bf16split(v0, h2.x, l2.x); bf16split(v1, h2.y, l2.y);
  *(short2*)&hP[oP] = h2; *(short2*)&hP[oP + 32] = l2;
}

// Acat packed [n][SPP2]: cols 0-449 = emb, 450-899 = sum h_nei, 900-959 = 0
__global__ void k_nodecat(const float* __restrict__ emb,
                          const int* __restrict__ fnode,
                          const short* __restrict__ hP,
                          const int* __restrict__ ng,
                          short* __restrict__ Apk) {
  int n = blockIdx.x, t = threadIdx.x, j = t * 2;
  if (j < H) {
    float2 v = *(const float2*)&emb[(size_t)fnode[n] * H + j];
    short2 h2, l2;
    bf16split(v.x, h2.x, l2.x); bf16split(v.y, h2.y, l2.y);
    size_t o = ppix(n, j, SPP2);
    *(short2*)&Apk[o] = h2; *(short2*)&Apk[o + 32] = l2;

    const int* e = ng + (size_t)n * KN;
    float s0 = 0.f, s1 = 0.f;
#pragma unroll
    for (int k = 0; k < KN; ++k) {
      size_t oP = ppix(e[k], j, SPP1);
      short2 ph = *(const short2*)&hP[oP];
      short2 pl = *(const short2*)&hP[oP + 32];
      s0 += bf16tof(ph.x) + bf16tof(pl.x);
      s1 += bf16tof(ph.y) + bf16tof(pl.y);
    }
    bf16split(s0, h2.x, l2.x); bf16split(s1, h2.y, l2.y);
    o = ppix(n, 450 + j, SPP2);
    *(short2*)&Apk[o] = h2; *(short2*)&Apk[o + 32] = l2;
  }
  if (t < 30) {   // zero cols [900,960)
    int c = 900 + t * 2;
    short2 z2; z2.x = 0; z2.y = 0;
    size_t o = ppix(n, c, SPP2);
    *(short2*)&Apk[o] = z2; *(short2*)&Apk[o + 32] = z2;
  }
}

// ---------------- launch ----------------

extern "C" void kernel_launch(void* const* d_in, const int* in_sizes, int n_in,
                              void* d_out, int out_size, void* d_ws, size_t ws_size,
                              hipStream_t stream) {
  (void)in_sizes; (void)n_in; (void)out_size; (void)ws_size;

  const int*   fnode      = (const int*)d_in[0];
  const int*   fmess      = (const int*)d_in[1];
  const int*   node_graph = (const int*)d_in[2];
  const int*   mess_graph = (const int*)d_in[3];
  const float* emb        = (const float*)d_in[4];
  const float* Wz         = (const float*)d_in[5];
  const float* bz         = (const float*)d_in[6];
  const float* Wr         = (const float*)d_in[7];
  const float* Ur         = (const float*)d_in[8];
  const float* bu         = (const float*)d_in[9];
  const float* Wh         = (const float*)d_in[10];
  const float* bh         = (const float*)d_in[11];
  const float* Wo         = (const float*)d_in[12];
  const float* bo         = (const float*)d_in[13];

  // ---- workspace: 3 packed planes + CHb + GU + r1b + tzb + thb ≈ 128.5 MB ----
  short* P   = (short*)d_ws;
  short* hP  = P;                     // h packed
  short* shP = P + 1 * PPSZ;          // sum_h packed (later Acat @ SPP2)
  short* ghP = P + 2 * PPSZ;          // sum_gh packed (also fmess_e packed)
  short* CHb = P + 3 * PPSZ;                       // [M][960] bf16: c_z | c_h
  short* GU  = CHb + (size_t)NMESS * LDCH;         // [M][960] bf16: g | u
  short* r1b = GU  + (size_t)NMESS * LDCH;         // [M][480] bf16
  short* tzb = r1b + (size_t)NMESS * 480;          // [M][480] bf16
  short* thb = tzb + (size_t)NMESS * 480;          // [M][480] bf16

  // ---- d_out messages region: packed weights (~8.7 of 18.4 MB) ----
  char*  scr  = (char*)d_out + (size_t)NNODE * H * 4;   // 16B-aligned
  short* BtI  = (short*)scr;                    // [1408][960] packed (WzT|WhT)
  short* BtR  = BtI  + (size_t)1408 * SPP1;     // [512][960] Wr
  short* BtGU = BtR  + (size_t)512 * SPP1;      // [1024][960]: Ur rows 0-449, WzB rows 450-899
  short* BtHH = BtGU + (size_t)1024 * SPP1;     // [512][960] Wh bottom
  short* BtO  = BtHH + (size_t)512 * SPP1;      // [512][1920] Wo
  float* biasI = (float*)(BtO + (size_t)512 * SPP2);    // [900]
  int*   idxM  = (int*)(biasI + 912);

  k_build_idx<<<(NMESS + 255) / 256, 256, 0, stream>>>(fnode, fmess, idxM);

  // packed weight prep (fully overwrites every region read later)
  dim3 gT(KP / 32, 16), gT2(KP2 / 32, 16);
  k_wT<<<gT,  256, 0, stream>>>(Wz,                  H, BtI,               KP,  512);
  k_wT<<<gT,  256, 0, stream>>>(Wh,                  H, BtI + 450 * SPP1,  KP,  512);
  k_wT<<<gT,  256, 0, stream>>>(Wr,                  H, BtR,               KP,  512);
  k_wT<<<gT,  256, 0, stream>>>(Ur,                  H, BtGU,              KP,  512);
  k_wT<<<gT,  256, 0, stream>>>(Wz + (size_t)H * H,  H, BtGU + 450 * SPP1, KP,  512);
  k_wT<<<gT,  256, 0, stream>>>(Wh + (size_t)H * H,  H, BtHH,              KP,  512);
  k_wT<<<gT2, 256, 0, stream>>>(Wo,                 H2, BtO,               KP2, 512);
  k_biascat<<<4, 256, 0, stream>>>(bz, bh, biasI);

  // fmess_e packed into ghP (writes K-tail zeros inline)
  k_embsplit<<<NMESS, 256, 0, stream>>>(emb, idxM, ghP);

  // invariant GEMMs: CHb (c_z|c_h, bf16) and r1b (bf16)
  dim3 gI1(15, MPAD / BM);   // N=900
  gemm4_b<<<gI1, 256, 0, stream>>>(ghP, KP, BtI, biasI, CHb, LDCH, NMESS, H2);
  dim3 gI2(8, MPAD / BM);    // N=450
  gemm4_b<<<gI2, 256, 0, stream>>>(ghP, KP, BtR, bu, r1b, 480, NMESS, H);

  // step 0 shortcut: h1 = mask * sigmoid(c_z) * tanh(c_h)
  k_h1<<<NMESS, 256, 0, stream>>>(CHb, hP);

  dim3 gGU(15, MPAD / BM);   // N=900: [g|u] = h @ [Ur|WzB]
  dim3 gB(8, MPAD / BM);     // N=450: t_h
  for (int d = 1; d < 8; ++d) {
    gemm4_b<<<gGU, 256, 0, stream>>>(hP, KP, BtGU, nullptr, GU, LDCH, NMESS, H2);
    k_gather3<<<NMESS, 256, 0, stream>>>(hP, GU, r1b, mess_graph, shP, ghP, tzb);
    gemm4_b<<<gB, 256, 0, stream>>>(ghP, KP, BtHH, nullptr, thb, 480, NMESS, H);
    k_combine<<<NMESS, 256, 0, stream>>>(CHb, tzb, thb, shP, hP);
  }

  // Acat packed (SPP2) then output GEMM with relu
  k_nodecat<<<NNODE, 256, 0, stream>>>(emb, fnode, hP, node_graph, shP);
  dim3 gF(8, NNODE / BM);    // (8, 80)
  gemm4<1><<<gF, 256, 0, stream>>>(shP, KP2, BtO, bo, (float*)d_out, H, NNODE, H);

  // messages output = zeros (wipes idx + weights) — AFTER final GEMM
  hipMemsetAsync((float*)d_out + (size_t)NNODE * H, 0, (size_t)NMESS * H * sizeof(float), stream);
}

// Round 15
// 827.556 us; speedup vs baseline: 2.6542x; 1.1142x over previous
//
#include <hip/hip_runtime.h>
#include <cstdint>
#include <cstddef>

#define H 450
#define H2 900
#define KP 480
#define KP2 960
#define NMESS 10241
#define NNODE 5120
#define MPAD 10368                 // 162 * 64
#define SPP1 960                   // packed row stride (shorts) for Kpad=480
#define SPP2 1920                  // for Kpad=960
#define PPSZ ((size_t)MPAD * SPP1) // packed plane size in shorts
#define KM 5
#define KN 6
#define LDCH 960                   // CHb row stride (bf16)

typedef __attribute__((ext_vector_type(8))) short short8;   // 8 bf16
typedef __attribute__((ext_vector_type(4))) float f32x4;

__device__ __forceinline__ short bf16rne(float f) {
  union { float f; unsigned u; } x; x.f = f;
  unsigned u = x.u;
  u += 0x7FFF + ((u >> 16) & 1);
  return (short)(u >> 16);
}
__device__ __forceinline__ float bf16tof(short s) {
  union { float f; unsigned u; } x;
  x.u = ((unsigned)(unsigned short)s) << 16;
  return x.f;
}
__device__ __forceinline__ void bf16split(float v, short& hi, short& lo) {
  hi = bf16rne(v);
  lo = bf16rne(v - bf16tof(hi));
}
__device__ __forceinline__ float sigmoidf_(float x) {
  return 1.f / (1.f + __expf(-x));
}

// packed element offset: hi at PPIX, lo at PPIX+32
__device__ __forceinline__ size_t ppix(int row, int k, int spp) {
  return (size_t)row * spp + ((k >> 5) << 6) + (k & 31);
}

// direct global->LDS 16B DMA (LDS dest: wave-uniform base + lane*16)
__device__ __forceinline__ void gll16(const short* g, short* l) {
  __builtin_amdgcn_global_load_lds(
      (const __attribute__((address_space(1))) void*)g,
      (__attribute__((address_space(3))) void*)l, 16, 0, 0);
}

// ---------------- split-bf16 MFMA GEMM: packed planes (r11-proven core) ----
// A,B packed [row][k-chunk][hi*32|lo*32] bf16. 256 thr (4 waves, 32x32 wave
// tiles), BK=32, 2-buf 32 KB LDS -> 5 blocks/CU. gload_lds staging: one
// contiguous 128B run per row per chunk; source slot = (lane&7)^(row&7),
// read-side XOR matches. XCD-chunked block swizzle.
#define BM 64
#define BN 64
#define BK 32

struct SmemT { short As[2][64][64]; short Bs[2][64][64]; };   // 32 KB

__device__ __forceinline__ void xcd_swz(int gx, int gy, int& bm, int& bn) {
  const int nwg = gx * gy;
  int lid = blockIdx.y * gx + blockIdx.x;
  const int q = nwg >> 3, r = nwg & 7;
  const int xcd = lid & 7, seq = lid >> 3;
  int sid = (xcd < r) ? (xcd * (q + 1) + seq)
                      : (r * (q + 1) + (xcd - r) * q + seq);
  bm = (sid / gx) * BM;
  bn = (sid % gx) * BN;
}

// OUT: 0 = f32 C (+bias, opt relu)
//      3 = single bf16 (Cs, stride ldc), +bias
template<int ACT, int OUT>
__device__ __forceinline__ void gemm_core(
    SmemT& sm, const short* __restrict__ Apk, int Kpad,
    const short* __restrict__ Bpk,
    const float* __restrict__ bias,
    float* C, int ldc, short* Cs,
    int M, int N, int bm, int bn)
{
  const int tid  = threadIdx.x;
  const int lane = tid & 63;
  const int wid  = tid >> 6;          // 0..3
  const int wm   = (wid >> 1) * 32;
  const int wn   = (wid & 1) * 32;
  const int l15  = lane & 15;
  const int s8   = (lane >> 4) * 8;   // k sub-offset in halves
  const int rr0  = (lane >> 4) * 4;
  const int spp  = Kpad * 2;

  // staging: unified 128 rows (0-63 = A, 64-127 = B); wave wid -> rows 32w..32w+31
  const int lr = lane >> 3;
  const int sl = lane & 7;
  const int t0 = sl ^ lr;             // packed slot (0-3 hi, 4-7 lo)
  const short* src[4];
#pragma unroll
  for (int qq = 0; qq < 4; ++qq) {
    const int rrow = wid * 32 + qq * 8 + lr;
    const bool isA = rrow < 64;
    const int grow = isA ? (bm + rrow) : (bn + rrow - 64);
    src[qq] = (isA ? Apk : Bpk) + (size_t)grow * spp + t0 * 8;
  }
  const int nk = Kpad / BK;

  f32x4 acc[2][2];
#pragma unroll
  for (int i = 0; i < 2; ++i)
#pragma unroll
    for (int j = 0; j < 2; ++j)
#pragma unroll
      for (int t = 0; t < 4; ++t) acc[i][j][t] = 0.f;

  auto STAGE = [&](int b, int koff) {
#pragma unroll
    for (int qq = 0; qq < 4; ++qq) {
      const int r0 = wid * 32 + qq * 8;
      short* d = (r0 < 64) ? &sm.As[b][r0][0] : &sm.Bs[b][r0 - 64][0];
      gll16(src[qq] + koff, d);
    }
  };

  STAGE(0, 0);
  __syncthreads();
  int cur = 0;
  for (int t = 0; t < nk; ++t) {
    if (t + 1 < nk) STAGE(cur ^ 1, (t + 1) * 64);
    short8 ah[2], al[2], bh[2], bl[2];
#pragma unroll
    for (int i = 0; i < 2; ++i) {
      const int rA = wm + i*16 + l15;
      const int xr = (rA & 7) << 3;
      ah[i] = *(const short8*)&sm.As[cur][rA][(s8)      ^ xr];
      al[i] = *(const short8*)&sm.As[cur][rA][(s8 + 32) ^ xr];
    }
#pragma unroll
    for (int j = 0; j < 2; ++j) {
      const int rB = wn + j*16 + l15;
      const int xr = (rB & 7) << 3;
      bh[j] = *(const short8*)&sm.Bs[cur][rB][(s8)      ^ xr];
      bl[j] = *(const short8*)&sm.Bs[cur][rB][(s8 + 32) ^ xr];
    }
    __builtin_amdgcn_s_setprio(1);
#pragma unroll
    for (int j = 0; j < 2; ++j)
#pragma unroll
      for (int i = 0; i < 2; ++i) {
        acc[i][j] = __builtin_amdgcn_mfma_f32_16x16x32_bf16(ah[i], bh[j], acc[i][j], 0, 0, 0);
        acc[i][j] = __builtin_amdgcn_mfma_f32_16x16x32_bf16(al[i], bh[j], acc[i][j], 0, 0, 0);
        acc[i][j] = __builtin_amdgcn_mfma_f32_16x16x32_bf16(ah[i], bl[j], acc[i][j], 0, 0, 0);
      }
    __builtin_amdgcn_s_setprio(0);
    __syncthreads();   // drains next-tile gload_lds + read/write order
    cur ^= 1;
  }

#pragma unroll
  for (int j = 0; j < 2; ++j) {
    int col = bn + wn + j*16 + l15;
    if (col >= N) continue;
    float bv = bias ? bias[col] : 0.f;
#pragma unroll
    for (int i = 0; i < 2; ++i) {
      int row0 = bm + wm + i*16 + rr0;
#pragma unroll
      for (int rr = 0; rr < 4; ++rr) {
        int row = row0 + rr;
        if (row >= M) continue;
        float v = acc[i][j][rr] + bv;
        if (OUT == 0) {
          if (ACT == 1) v = fmaxf(v, 0.f);
          C[(size_t)row * ldc + col] = v;
        } else {  // OUT == 3: single bf16, stride ldc
          Cs[(size_t)row * ldc + col] = bf16rne(v);
        }
      }
    }
  }
}

template<int ACT>
__global__ __launch_bounds__(256, 5)
void gemm4(const short* __restrict__ Apk, int Kpad,
           const short* __restrict__ Bpk,
           const float* __restrict__ bias,
           float* C, int ldc, int M, int N)
{
  __shared__ SmemT sm;
  int bm, bn; xcd_swz(gridDim.x, gridDim.y, bm, bn);
  gemm_core<ACT, 0>(sm, Apk, Kpad, Bpk, bias, C, ldc, nullptr, M, N, bm, bn);
}

// single-bf16 output GEMM (CHb, r1b, gb)
__global__ __launch_bounds__(256, 5)
void gemm4_b(const short* __restrict__ Apk, int Kpad,
             const short* __restrict__ Bpk,
             const float* __restrict__ bias,
             short* Cs, int ldcs, int M, int N)
{
  __shared__ SmemT sm;
  int bm, bn; xcd_swz(gridDim.x, gridDim.y, bm, bn);
  gemm_core<0, 3>(sm, Apk, Kpad, Bpk, bias, nullptr, ldcs, Cs, M, N, bm, bn);
}

// grouped pair: z=0: thb = ghP@WhB ; z=1: tzb = shP@WzB   (both bf16 [M][480])
__global__ __launch_bounds__(256, 5)
void gemm4_pair(const short* __restrict__ A0, const short* __restrict__ B0,
                short* C0,
                const short* __restrict__ A1, const short* __restrict__ B1,
                short* C1)
{
  __shared__ SmemT sm;
  int bm, bn; xcd_swz(gridDim.x, gridDim.y, bm, bn);
  if (blockIdx.z == 0)
    gemm_core<0, 3>(sm, A0, KP, B0, nullptr, nullptr, 480, C0, NMESS, H, bm, bn);
  else
    gemm_core<0, 3>(sm, A1, KP, B1, nullptr, nullptr, 480, C1, NMESS, H, bm, bn);
}

// ---------------- weight transpose + packed bf16 hi/lo split ----------------
// Bt packed [c][chunk][hi|lo], c = column of original W; c < rmax written
__global__ __launch_bounds__(256)
void k_wT(const float* __restrict__ W, int Kreal,
          short* __restrict__ Bt, int Kpad, int rmax) {
  __shared__ float T[32][33];
  const int tx = threadIdx.x & 31;
  const int ty = threadIdx.x >> 5;
  const int k0 = blockIdx.x * 32;
  const int c0 = blockIdx.y * 32;
  const int spp = Kpad * 2;
#pragma unroll
  for (int i = 0; i < 4; ++i) {
    int k = k0 + ty + i*8, c = c0 + tx;
    T[ty + i*8][tx] = (k < Kreal && c < H) ? W[(size_t)k * H + c] : 0.f;
  }
  __syncthreads();
#pragma unroll
  for (int i = 0; i < 4; ++i) {
    int c = c0 + ty + i*8, k = k0 + tx;
    if (k < Kpad && c < rmax) {
      short hi, lo;
      bf16split(T[tx][ty + i*8], hi, lo);
      size_t o = ppix(c, k, spp);
      Bt[o] = hi; Bt[o + 32] = lo;
    }
  }
}

__global__ void k_biascat(const float* __restrict__ bz, const float* __restrict__ bh,
                          float* __restrict__ biasI) {
  int c = blockIdx.x * blockDim.x + threadIdx.x;
  if (c >= 900) return;
  biasI[c] = (c < 450) ? bz[c] : bh[c - 450];
}

// ---------------- elementwise / gather kernels ----------------

__global__ void k_build_idx(const int* __restrict__ fnode,
                            const int* __restrict__ fmess,
                            int* __restrict__ idxM) {
  int m = blockIdx.x * blockDim.x + threadIdx.x;
  if (m < NMESS) idxM[m] = fnode[fmess[m]];
}

__global__ void k_embsplit(const float* __restrict__ emb,
                           const int* __restrict__ idxM,
                           short* __restrict__ eP) {
  int m = blockIdx.x, j = threadIdx.x * 2;
  if (j >= KP) return;
  size_t o = ppix(m, j, SPP1);
  if (j < H) {
    float2 v = *(const float2*)&emb[(size_t)idxM[m] * H + j];
    short2 h2, l2;
    bf16split(v.x, h2.x, l2.x); bf16split(v.y, h2.y, l2.y);
    *(short2*)&eP[o] = h2; *(short2*)&eP[o + 32] = l2;
  } else {                      // K-tail cols [450,480) must be 0
    short2 z2; z2.x = 0; z2.y = 0;
    *(short2*)&eP[o] = z2; *(short2*)&eP[o + 32] = z2;
  }
}

// step 0: h1 = mask * sigmoid(c_z) * tanh(c_h)   (sum_h = t_z = t_h = 0)
__global__ void k_h1(const short* __restrict__ CHb, short* __restrict__ hP) {
  int m = blockIdx.x, j = threadIdx.x * 2;
  if (j >= KP) return;
  size_t oP = ppix(m, j, SPP1);
  if (j < H) {
    size_t oc = (size_t)m * LDCH + j;
    short2 cz2 = *(const short2*)&CHb[oc];
    short2 ch2 = *(const short2*)&CHb[oc + 450];
    float v0 = sigmoidf_(bf16tof(cz2.x)) * tanhf(bf16tof(ch2.x));
    float v1 = sigmoidf_(bf16tof(cz2.y)) * tanhf(bf16tof(ch2.y));
    if (m == 0) { v0 = 0.f; v1 = 0.f; }
    short2 h2, l2;
    bf16split(v0, h2.x, l2.x); bf16split(v1, h2.y, l2.y);
    *(short2*)&hP[oP] = h2; *(short2*)&hP[oP + 32] = l2;
  } else {
    short2 z2; z2.x = 0; z2.y = 0;
    *(short2*)&hP[oP] = z2; *(short2*)&hP[oP + 32] = z2;
  }
}

// one pass over neighbors: sum_h (packed) + sum_gh (packed)
// gb = h@Ur, bf16 [M][480]
__global__ void k_gather2(const short* __restrict__ hP,
                          const short* __restrict__ gb,
                          const short* __restrict__ r1b,   // [M][480] bf16
                          const int* __restrict__ mg,
                          short* __restrict__ shP, short* __restrict__ ghP) {
  int m = blockIdx.x, j = threadIdx.x * 2;
  if (j >= KP) return;
  size_t o = ppix(m, j, SPP1);
  if (j >= H) {                 // K-tail zeros
    short2 z2; z2.x = 0; z2.y = 0;
    *(short2*)&shP[o] = z2; *(short2*)&shP[o + 32] = z2;
    *(short2*)&ghP[o] = z2; *(short2*)&ghP[o + 32] = z2;
    return;
  }
  const int* e = mg + (size_t)m * KM;
  short2 rb2 = *(const short2*)&r1b[(size_t)m * 480 + j];
  float rb0 = bf16tof(rb2.x), rb1 = bf16tof(rb2.y);
  float s0 = 0.f, s1 = 0.f, t0 = 0.f, t1 = 0.f;
#pragma unroll
  for (int k = 0; k < KM; ++k) {
    int ek = e[k];
    size_t oP = ppix(ek, j, SPP1);
    short2 gv = *(const short2*)&gb[(size_t)ek * 480 + j];
    short2 ph = *(const short2*)&hP[oP];
    short2 pl = *(const short2*)&hP[oP + 32];
    float h0 = bf16tof(ph.x) + bf16tof(pl.x);
    float h1 = bf16tof(ph.y) + bf16tof(pl.y);
    s0 += h0;                                  s1 += h1;
    t0 += sigmoidf_(rb0 + bf16tof(gv.x)) * h0; t1 += sigmoidf_(rb1 + bf16tof(gv.y)) * h1;
  }
  short2 h2, l2;
  bf16split(s0, h2.x, l2.x); bf16split(s1, h2.y, l2.y);
  *(short2*)&shP[o] = h2; *(short2*)&shP[o + 32] = l2;
  bf16split(t0, h2.x, l2.x); bf16split(t1, h2.y, l2.y);
  *(short2*)&ghP[o] = h2; *(short2*)&ghP[o + 32] = l2;
}

// h = mask*((1-z)*sum_h + z*tanh(c_h+t_h)); coalesced, in place on hP
__global__ void k_combine(const short* __restrict__ CHb,   // [M][960] bf16: c_z|c_h
                          const short* __restrict__ tzb,   // [M][480] bf16
                          const short* __restrict__ thb,   // [M][480] bf16
                          const short* __restrict__ shP,
                          short* hP) {
  int m = blockIdx.x, j = threadIdx.x * 2;
  if (j >= H) return;           // K-tail of hP stays zero (only h1/combine write hP)
  size_t oc = (size_t)m * LDCH + j;
  size_t oP = ppix(m, j, SPP1);
  short2 cz2 = *(const short2*)&CHb[oc];
  short2 ch2 = *(const short2*)&CHb[oc + 450];
  short2 tz2 = *(const short2*)&tzb[(size_t)m * 480 + j];
  short2 th2 = *(const short2*)&thb[(size_t)m * 480 + j];
  short2 smh = *(const short2*)&shP[oP];
  short2 sml = *(const short2*)&shP[oP + 32];
  float sm0 = bf16tof(smh.x) + bf16tof(sml.x);
  float sm1 = bf16tof(smh.y) + bf16tof(sml.y);
  float z0 = sigmoidf_(bf16tof(cz2.x) + bf16tof(tz2.x));
  float z1 = sigmoidf_(bf16tof(cz2.y) + bf16tof(tz2.y));
  float p0 = tanhf(bf16tof(ch2.x) + bf16tof(th2.x));
  float p1 = tanhf(bf16tof(ch2.y) + bf16tof(th2.y));
  float v0 = (1.f - z0) * sm0 + z0 * p0;
  float v1 = (1.f - z1) * sm1 + z1 * p1;
  if (m == 0) { v0 = 0.f; v1 = 0.f; }
  short2 h2, l2;
  bf16split(v0, h2.x, l2.x); bf16split(v1, h2.y, l2.y);
  *(short2*)&hP[oP] = h2; *(short2*)&hP[oP + 32] = l2;
}

// Acat packed [n][SPP2]: cols 0-449 = emb, 450-899 = sum h_nei, 900-959 = 0
__global__ void k_nodecat(const float* __restrict__ emb,
                          const int* __restrict__ fnode,
                          const short* __restrict__ hP,
                          const int* __restrict__ ng,
                          short* __restrict__ Apk) {
  int n = blockIdx.x, t = threadIdx.x, j = t * 2;
  if (j < H) {
    float2 v = *(const float2*)&emb[(size_t)fnode[n] * H + j];
    short2 h2, l2;
    bf16split(v.x, h2.x, l2.x); bf16split(v.y, h2.y, l2.y);
    size_t o = ppix(n, j, SPP2);
    *(short2*)&Apk[o] = h2; *(short2*)&Apk[o + 32] = l2;

    const int* e = ng + (size_t)n * KN;
    float s0 = 0.f, s1 = 0.f;
#pragma unroll
    for (int k = 0; k < KN; ++k) {
      size_t oP = ppix(e[k], j, SPP1);
      short2 ph = *(const short2*)&hP[oP];
      short2 pl = *(const short2*)&hP[oP + 32];
      s0 += bf16tof(ph.x) + bf16tof(pl.x);
      s1 += bf16tof(ph.y) + bf16tof(pl.y);
    }
    bf16split(s0, h2.x, l2.x); bf16split(s1, h2.y, l2.y);
    o = ppix(n, 450 + j, SPP2);
    *(short2*)&Apk[o] = h2; *(short2*)&Apk[o + 32] = l2;
  }
  if (t < 30) {   // zero cols [900,960)
    int c = 900 + t * 2;
    short2 z2; z2.x = 0; z2.y = 0;
    size_t o = ppix(n, c, SPP2);
    *(short2*)&Apk[o] = z2; *(short2*)&Apk[o + 32] = z2;
  }
}

// ---------------- launch ----------------

extern "C" void kernel_launch(void* const* d_in, const int* in_sizes, int n_in,
                              void* d_out, int out_size, void* d_ws, size_t ws_size,
                              hipStream_t stream) {
  (void)in_sizes; (void)n_in; (void)out_size; (void)ws_size;

  const int*   fnode      = (const int*)d_in[0];
  const int*   fmess      = (const int*)d_in[1];
  const int*   node_graph = (const int*)d_in[2];
  const int*   mess_graph = (const int*)d_in[3];
  const float* emb        = (const float*)d_in[4];
  const float* Wz         = (const float*)d_in[5];
  const float* bz         = (const float*)d_in[6];
  const float* Wr         = (const float*)d_in[7];
  const float* Ur         = (const float*)d_in[8];
  const float* bu         = (const float*)d_in[9];
  const float* Wh         = (const float*)d_in[10];
  const float* bh         = (const float*)d_in[11];
  const float* Wo         = (const float*)d_in[12];
  const float* bo         = (const float*)d_in[13];

  // ---- workspace: 3 packed planes + CHb + gb + r1b + tzb + thb ≈ 118.7 MB ----
  short* P   = (short*)d_ws;
  short* hP  = P;                     // h packed
  short* shP = P + 1 * PPSZ;          // sum_h packed (later Acat @ SPP2)
  short* ghP = P + 2 * PPSZ;          // sum_gh packed (also fmess_e packed)
  short* CHb = P + 3 * PPSZ;                       // [M][960] bf16: c_z | c_h
  short* gb  = CHb + (size_t)NMESS * LDCH;         // [M][480] bf16: h@Ur
  short* r1b = gb  + (size_t)NMESS * 480;          // [M][480] bf16
  short* tzb = r1b + (size_t)NMESS * 480;          // [M][480] bf16
  short* thb = tzb + (size_t)NMESS * 480;          // [M][480] bf16

  // ---- d_out messages region: packed weights (~8.7 of 18.4 MB) ----
  char*  scr  = (char*)d_out + (size_t)NNODE * H * 4;   // 16B-aligned
  short* BtI  = (short*)scr;                    // [1408][960] packed (WzT|WhT)
  short* BtR  = BtI  + (size_t)1408 * SPP1;     // [512][960] Wr
  short* BtUr = BtR  + (size_t)512 * SPP1;      // [512][960] Ur
  short* BtZ  = BtUr + (size_t)512 * SPP1;      // [512][960] Wz bottom
  short* BtHH = BtZ  + (size_t)512 * SPP1;      // [512][960] Wh bottom
  short* BtO  = BtHH + (size_t)512 * SPP1;      // [512][1920] Wo
  float* biasI = (float*)(BtO + (size_t)512 * SPP2);    // [900]
  int*   idxM  = (int*)(biasI + 912);

  k_build_idx<<<(NMESS + 255) / 256, 256, 0, stream>>>(fnode, fmess, idxM);

  // packed weight prep (fully overwrites every region read later)
  dim3 gT(KP / 32, 16), gT2(KP2 / 32, 16);
  k_wT<<<gT,  256, 0, stream>>>(Wz,                  H, BtI,               KP,  512);
  k_wT<<<gT,  256, 0, stream>>>(Wh,                  H, BtI + 450 * SPP1,  KP,  512);
  k_wT<<<gT,  256, 0, stream>>>(Wr,                  H, BtR,               KP,  512);
  k_wT<<<gT,  256, 0, stream>>>(Ur,                  H, BtUr,              KP,  512);
  k_wT<<<gT,  256, 0, stream>>>(Wz + (size_t)H * H,  H, BtZ,               KP,  512);
  k_wT<<<gT,  256, 0, stream>>>(Wh + (size_t)H * H,  H, BtHH,              KP,  512);
  k_wT<<<gT2, 256, 0, stream>>>(Wo,                 H2, BtO,               KP2, 512);
  k_biascat<<<4, 256, 0, stream>>>(bz, bh, biasI);

  // fmess_e packed into ghP (writes K-tail zeros inline)
  k_embsplit<<<NMESS, 256, 0, stream>>>(emb, idxM, ghP);

  // invariant GEMMs: CHb (c_z|c_h, bf16) and r1b (bf16)
  dim3 gI1(15, MPAD / BM);   // N=900
  gemm4_b<<<gI1, 256, 0, stream>>>(ghP, KP, BtI, biasI, CHb, LDCH, NMESS, H2);
  dim3 gI2(8, MPAD / BM);    // N=450
  gemm4_b<<<gI2, 256, 0, stream>>>(ghP, KP, BtR, bu, r1b, 480, NMESS, H);

  // step 0 shortcut: h1 = mask * sigmoid(c_z) * tanh(c_h)
  k_h1<<<NMESS, 256, 0, stream>>>(CHb, hP);

  dim3 gB(8, MPAD / BM);     // (8, 162)
  dim3 gP(8, MPAD / BM, 2);  // grouped t_h + t_z
  for (int d = 1; d < 8; ++d) {
    // gb = h @ Ur (bf16)
    gemm4_b<<<gB, 256, 0, stream>>>(hP, KP, BtUr, nullptr, gb, 480, NMESS, H);
    // sum_h & sum_gh packed in one pass
    k_gather2<<<NMESS, 256, 0, stream>>>(hP, gb, r1b, mess_graph, shP, ghP);
    // thb = ghP@WhB  ||  tzb = shP@WzB   (grouped)
    gemm4_pair<<<gP, 256, 0, stream>>>(ghP, BtHH, thb, shP, BtZ, tzb);
    // combine in place -> hP
    k_combine<<<NMESS, 256, 0, stream>>>(CHb, tzb, thb, shP, hP);
  }

  // Acat packed (SPP2) then output GEMM with relu
  k_nodecat<<<NNODE, 256, 0, stream>>>(emb, fnode, hP, node_graph, shP);
  dim3 gF(8, NNODE / BM);    // (8, 80)
  gemm4<1><<<gF, 256, 0, stream>>>(shP, KP2, BtO, bo, (float*)d_out, H, NNODE, H);

  // messages output = zeros (wipes idx + weights) — AFTER final GEMM
  hipMemsetAsync((float*)d_out + (size_t)NNODE * H, 0, (size_t)NMESS * H * sizeof(float), stream);
}

// Round 16
// 809.066 us; speedup vs baseline: 2.7148x; 1.0229x over previous
//
#include <hip/hip_runtime.h>
#include <cstdint>
#include <cstddef>

#define H 450
#define H2 900
#define KP 480
#define KP2 960
#define NMESS 10241
#define NNODE 5120
#define MPAD 10368                 // 162 * 64
#define SPP1 960                   // packed row stride (shorts) for Kpad=480
#define SPP2 1920                  // for Kpad=960
#define PPSZ ((size_t)MPAD * SPP1) // packed plane size in shorts
#define KM 5
#define KN 6
#define LDCH 960                   // CHb row stride (bf16)

typedef __attribute__((ext_vector_type(8))) short short8;   // 8 bf16
typedef __attribute__((ext_vector_type(4))) float f32x4;

__device__ __forceinline__ short bf16rne(float f) {
  union { float f; unsigned u; } x; x.f = f;
  unsigned u = x.u;
  u += 0x7FFF + ((u >> 16) & 1);
  return (short)(u >> 16);
}
__device__ __forceinline__ float bf16tof(short s) {
  union { float f; unsigned u; } x;
  x.u = ((unsigned)(unsigned short)s) << 16;
  return x.f;
}
__device__ __forceinline__ void bf16split(float v, short& hi, short& lo) {
  hi = bf16rne(v);
  lo = bf16rne(v - bf16tof(hi));
}
__device__ __forceinline__ float sigmoidf_(float x) {
  return 1.f / (1.f + __expf(-x));
}

// packed element offset: hi at PPIX, lo at PPIX+32
__device__ __forceinline__ size_t ppix(int row, int k, int spp) {
  return (size_t)row * spp + ((k >> 5) << 6) + (k & 31);
}

// direct global->LDS 16B DMA (LDS dest: wave-uniform base + lane*16)
__device__ __forceinline__ void gll16(const short* g, short* l) {
  __builtin_amdgcn_global_load_lds(
      (const __attribute__((address_space(1))) void*)g,
      (__attribute__((address_space(3))) void*)l, 16, 0, 0);
}

// ---------------- split-bf16 MFMA GEMM: packed planes (r11-proven core) ----
// A,B packed [row][k-chunk][hi*32|lo*32] bf16. 256 thr (4 waves, 32x32 wave
// tiles), BK=32, 2-buf 32 KB LDS -> 5 blocks/CU. gload_lds staging: one
// contiguous 128B run per row per chunk; source slot = (lane&7)^(row&7),
// read-side XOR matches. XCD-chunked block swizzle.
// PROD: 3 = full split (Ahi*Bhi + Alo*Bhi + Ahi*Blo), 2 = drop Ahi*Blo
// (full-precision activation x bf16 weight — for bf16-stored gate outputs).
#define BM 64
#define BN 64
#define BK 32

struct SmemT { short As[2][64][64]; short Bs[2][64][64]; };   // 32 KB

__device__ __forceinline__ void xcd_swz(int gx, int gy, int& bm, int& bn) {
  const int nwg = gx * gy;
  int lid = blockIdx.y * gx + blockIdx.x;
  const int q = nwg >> 3, r = nwg & 7;
  const int xcd = lid & 7, seq = lid >> 3;
  int sid = (xcd < r) ? (xcd * (q + 1) + seq)
                      : (r * (q + 1) + (xcd - r) * q + seq);
  bm = (sid / gx) * BM;
  bn = (sid % gx) * BN;
}

// OUT: 0 = f32 C (+bias, opt relu)
//      3 = single bf16 (Cs, stride ldc), +bias
template<int ACT, int OUT, int PROD>
__device__ __forceinline__ void gemm_core(
    SmemT& sm, const short* __restrict__ Apk, int Kpad,
    const short* __restrict__ Bpk,
    const float* __restrict__ bias,
    float* C, int ldc, short* Cs,
    int M, int N, int bm, int bn)
{
  const int tid  = threadIdx.x;
  const int lane = tid & 63;
  const int wid  = tid >> 6;          // 0..3
  const int wm   = (wid >> 1) * 32;
  const int wn   = (wid & 1) * 32;
  const int l15  = lane & 15;
  const int s8   = (lane >> 4) * 8;   // k sub-offset in halves
  const int rr0  = (lane >> 4) * 4;
  const int spp  = Kpad * 2;

  // staging: unified 128 rows (0-63 = A, 64-127 = B); wave wid -> rows 32w..32w+31
  const int lr = lane >> 3;
  const int sl = lane & 7;
  const int t0 = sl ^ lr;             // packed slot (0-3 hi, 4-7 lo)
  const short* src[4];
#pragma unroll
  for (int qq = 0; qq < 4; ++qq) {
    const int rrow = wid * 32 + qq * 8 + lr;
    const bool isA = rrow < 64;
    const int grow = isA ? (bm + rrow) : (bn + rrow - 64);
    src[qq] = (isA ? Apk : Bpk) + (size_t)grow * spp + t0 * 8;
  }
  const int nk = Kpad / BK;

  f32x4 acc[2][2];
#pragma unroll
  for (int i = 0; i < 2; ++i)
#pragma unroll
    for (int j = 0; j < 2; ++j)
#pragma unroll
      for (int t = 0; t < 4; ++t) acc[i][j][t] = 0.f;

  auto STAGE = [&](int b, int koff) {
#pragma unroll
    for (int qq = 0; qq < 4; ++qq) {
      const int r0 = wid * 32 + qq * 8;
      short* d = (r0 < 64) ? &sm.As[b][r0][0] : &sm.Bs[b][r0 - 64][0];
      gll16(src[qq] + koff, d);
    }
  };

  STAGE(0, 0);
  __syncthreads();
  int cur = 0;
  for (int t = 0; t < nk; ++t) {
    if (t + 1 < nk) STAGE(cur ^ 1, (t + 1) * 64);
    short8 ah[2], al[2], bh[2], bl[2];
#pragma unroll
    for (int i = 0; i < 2; ++i) {
      const int rA = wm + i*16 + l15;
      const int xr = (rA & 7) << 3;
      ah[i] = *(const short8*)&sm.As[cur][rA][(s8)      ^ xr];
      al[i] = *(const short8*)&sm.As[cur][rA][(s8 + 32) ^ xr];
    }
#pragma unroll
    for (int j = 0; j < 2; ++j) {
      const int rB = wn + j*16 + l15;
      const int xr = (rB & 7) << 3;
      bh[j] = *(const short8*)&sm.Bs[cur][rB][(s8)      ^ xr];
      if (PROD == 3)
        bl[j] = *(const short8*)&sm.Bs[cur][rB][(s8 + 32) ^ xr];
    }
    __builtin_amdgcn_s_setprio(1);
#pragma unroll
    for (int j = 0; j < 2; ++j)
#pragma unroll
      for (int i = 0; i < 2; ++i) {
        acc[i][j] = __builtin_amdgcn_mfma_f32_16x16x32_bf16(ah[i], bh[j], acc[i][j], 0, 0, 0);
        acc[i][j] = __builtin_amdgcn_mfma_f32_16x16x32_bf16(al[i], bh[j], acc[i][j], 0, 0, 0);
        if (PROD == 3)
          acc[i][j] = __builtin_amdgcn_mfma_f32_16x16x32_bf16(ah[i], bl[j], acc[i][j], 0, 0, 0);
      }
    __builtin_amdgcn_s_setprio(0);
    __syncthreads();   // drains next-tile gload_lds + read/write order
    cur ^= 1;
  }

#pragma unroll
  for (int j = 0; j < 2; ++j) {
    int col = bn + wn + j*16 + l15;
    if (col >= N) continue;
    float bv = bias ? bias[col] : 0.f;
#pragma unroll
    for (int i = 0; i < 2; ++i) {
      int row0 = bm + wm + i*16 + rr0;
#pragma unroll
      for (int rr = 0; rr < 4; ++rr) {
        int row = row0 + rr;
        if (row >= M) continue;
        float v = acc[i][j][rr] + bv;
        if (OUT == 0) {
          if (ACT == 1) v = fmaxf(v, 0.f);
          C[(size_t)row * ldc + col] = v;
        } else {  // OUT == 3: single bf16, stride ldc
          Cs[(size_t)row * ldc + col] = bf16rne(v);
        }
      }
    }
  }
}

template<int ACT>
__global__ __launch_bounds__(256, 5)
void gemm4(const short* __restrict__ Apk, int Kpad,
           const short* __restrict__ Bpk,
           const float* __restrict__ bias,
           float* C, int ldc, int M, int N)
{
  __shared__ SmemT sm;
  int bm, bn; xcd_swz(gridDim.x, gridDim.y, bm, bn);
  gemm_core<ACT, 0, 3>(sm, Apk, Kpad, Bpk, bias, C, ldc, nullptr, M, N, bm, bn);
}

// single-bf16 output GEMM; PROD = split products (3 = invariants, 2 = gates)
template<int PROD>
__global__ __launch_bounds__(256, 5)
void gemm4_b(const short* __restrict__ Apk, int Kpad,
             const short* __restrict__ Bpk,
             const float* __restrict__ bias,
             short* Cs, int ldcs, int M, int N)
{
  __shared__ SmemT sm;
  int bm, bn; xcd_swz(gridDim.x, gridDim.y, bm, bn);
  gemm_core<0, 3, PROD>(sm, Apk, Kpad, Bpk, bias, nullptr, ldcs, Cs, M, N, bm, bn);
}

// grouped pair: z=0: thb = ghP@WhB ; z=1: tzb = shP@WzB   (both bf16 [M][480])
__global__ __launch_bounds__(256, 5)
void gemm4_pair(const short* __restrict__ A0, const short* __restrict__ B0,
                short* C0,
                const short* __restrict__ A1, const short* __restrict__ B1,
                short* C1)
{
  __shared__ SmemT sm;
  int bm, bn; xcd_swz(gridDim.x, gridDim.y, bm, bn);
  if (blockIdx.z == 0)
    gemm_core<0, 3, 2>(sm, A0, KP, B0, nullptr, nullptr, 480, C0, NMESS, H, bm, bn);
  else
    gemm_core<0, 3, 2>(sm, A1, KP, B1, nullptr, nullptr, 480, C1, NMESS, H, bm, bn);
}

// ---------------- weight transpose + packed bf16 hi/lo split ----------------
// Bt packed [c][chunk][hi|lo], c = column of original W; c < rmax written
__global__ __launch_bounds__(256)
void k_wT(const float* __restrict__ W, int Kreal,
          short* __restrict__ Bt, int Kpad, int rmax) {
  __shared__ float T[32][33];
  const int tx = threadIdx.x & 31;
  const int ty = threadIdx.x >> 5;
  const int k0 = blockIdx.x * 32;
  const int c0 = blockIdx.y * 32;
  const int spp = Kpad * 2;
#pragma unroll
  for (int i = 0; i < 4; ++i) {
    int k = k0 + ty + i*8, c = c0 + tx;
    T[ty + i*8][tx] = (k < Kreal && c < H) ? W[(size_t)k * H + c] : 0.f;
  }
  __syncthreads();
#pragma unroll
  for (int i = 0; i < 4; ++i) {
    int c = c0 + ty + i*8, k = k0 + tx;
    if (k < Kpad && c < rmax) {
      short hi, lo;
      bf16split(T[tx][ty + i*8], hi, lo);
      size_t o = ppix(c, k, spp);
      Bt[o] = hi; Bt[o + 32] = lo;
    }
  }
}

__global__ void k_biascat(const float* __restrict__ bz, const float* __restrict__ bh,
                          float* __restrict__ biasI) {
  int c = blockIdx.x * blockDim.x + threadIdx.x;
  if (c >= 900) return;
  biasI[c] = (c < 450) ? bz[c] : bh[c - 450];
}

// ---------------- elementwise / gather kernels ----------------

__global__ void k_build_idx(const int* __restrict__ fnode,
                            const int* __restrict__ fmess,
                            int* __restrict__ idxM) {
  int m = blockIdx.x * blockDim.x + threadIdx.x;
  if (m < NMESS) idxM[m] = fnode[fmess[m]];
}

__global__ void k_embsplit(const float* __restrict__ emb,
                           const int* __restrict__ idxM,
                           short* __restrict__ eP) {
  int m = blockIdx.x, j = threadIdx.x * 2;
  if (j >= KP) return;
  size_t o = ppix(m, j, SPP1);
  if (j < H) {
    float2 v = *(const float2*)&emb[(size_t)idxM[m] * H + j];
    short2 h2, l2;
    bf16split(v.x, h2.x, l2.x); bf16split(v.y, h2.y, l2.y);
    *(short2*)&eP[o] = h2; *(short2*)&eP[o + 32] = l2;
  } else {                      // K-tail cols [450,480) must be 0
    short2 z2; z2.x = 0; z2.y = 0;
    *(short2*)&eP[o] = z2; *(short2*)&eP[o + 32] = z2;
  }
}

// step 0: h1 = mask * sigmoid(c_z) * tanh(c_h)   (sum_h = t_z = t_h = 0)
__global__ void k_h1(const short* __restrict__ CHb, short* __restrict__ hP) {
  int m = blockIdx.x, j = threadIdx.x * 2;
  if (j >= KP) return;
  size_t oP = ppix(m, j, SPP1);
  if (j < H) {
    size_t oc = (size_t)m * LDCH + j;
    short2 cz2 = *(const short2*)&CHb[oc];
    short2 ch2 = *(const short2*)&CHb[oc + 450];
    float v0 = sigmoidf_(bf16tof(cz2.x)) * tanhf(bf16tof(ch2.x));
    float v1 = sigmoidf_(bf16tof(cz2.y)) * tanhf(bf16tof(ch2.y));
    if (m == 0) { v0 = 0.f; v1 = 0.f; }
    short2 h2, l2;
    bf16split(v0, h2.x, l2.x); bf16split(v1, h2.y, l2.y);
    *(short2*)&hP[oP] = h2; *(short2*)&hP[oP + 32] = l2;
  } else {
    short2 z2; z2.x = 0; z2.y = 0;
    *(short2*)&hP[oP] = z2; *(short2*)&hP[oP + 32] = z2;
  }
}

// one pass over neighbors: sum_h (packed) + sum_gh (packed)
// gb = h@Ur, bf16 [M][480]
__global__ void k_gather2(const short* __restrict__ hP,
                          const short* __restrict__ gb,
                          const short* __restrict__ r1b,   // [M][480] bf16
                          const int* __restrict__ mg,
                          short* __restrict__ shP, short* __restrict__ ghP) {
  int m = blockIdx.x, j = threadIdx.x * 2;
  if (j >= KP) return;
  size_t o = ppix(m, j, SPP1);
  if (j >= H) {                 // K-tail zeros
    short2 z2; z2.x = 0; z2.y = 0;
    *(short2*)&shP[o] = z2; *(short2*)&shP[o + 32] = z2;
    *(short2*)&ghP[o] = z2; *(short2*)&ghP[o + 32] = z2;
    return;
  }
  const int* e = mg + (size_t)m * KM;
  short2 rb2 = *(const short2*)&r1b[(size_t)m * 480 + j];
  float rb0 = bf16tof(rb2.x), rb1 = bf16tof(rb2.y);
  float s0 = 0.f, s1 = 0.f, t0 = 0.f, t1 = 0.f;
#pragma unroll
  for (int k = 0; k < KM; ++k) {
    int ek = e[k];
    size_t oP = ppix(ek, j, SPP1);
    short2 gv = *(const short2*)&gb[(size_t)ek * 480 + j];
    short2 ph = *(const short2*)&hP[oP];
    short2 pl = *(const short2*)&hP[oP + 32];
    float h0 = bf16tof(ph.x) + bf16tof(pl.x);
    float h1 = bf16tof(ph.y) + bf16tof(pl.y);
    s0 += h0;                                  s1 += h1;
    t0 += sigmoidf_(rb0 + bf16tof(gv.x)) * h0; t1 += sigmoidf_(rb1 + bf16tof(gv.y)) * h1;
  }
  short2 h2, l2;
  bf16split(s0, h2.x, l2.x); bf16split(s1, h2.y, l2.y);
  *(short2*)&shP[o] = h2; *(short2*)&shP[o + 32] = l2;
  bf16split(t0, h2.x, l2.x); bf16split(t1, h2.y, l2.y);
  *(short2*)&ghP[o] = h2; *(short2*)&ghP[o + 32] = l2;
}

// h = mask*((1-z)*sum_h + z*tanh(c_h+t_h)); coalesced, in place on hP
__global__ void k_combine(const short* __restrict__ CHb,   // [M][960] bf16: c_z|c_h
                          const short* __restrict__ tzb,   // [M][480] bf16
                          const short* __restrict__ thb,   // [M][480] bf16
                          const short* __restrict__ shP,
                          short* hP) {
  int m = blockIdx.x, j = threadIdx.x * 2;
  if (j >= H) return;           // K-tail of hP stays zero (only h1/combine write hP)
  size_t oc = (size_t)m * LDCH + j;
  size_t oP = ppix(m, j, SPP1);
  short2 cz2 = *(const short2*)&CHb[oc];
  short2 ch2 = *(const short2*)&CHb[oc + 450];
  short2 tz2 = *(const short2*)&tzb[(size_t)m * 480 + j];
  short2 th2 = *(const short2*)&thb[(size_t)m * 480 + j];
  short2 smh = *(const short2*)&shP[oP];
  short2 sml = *(const short2*)&shP[oP + 32];
  float sm0 = bf16tof(smh.x) + bf16tof(sml.x);
  float sm1 = bf16tof(smh.y) + bf16tof(sml.y);
  float z0 = sigmoidf_(bf16tof(cz2.x) + bf16tof(tz2.x));
  float z1 = sigmoidf_(bf16tof(cz2.y) + bf16tof(tz2.y));
  float p0 = tanhf(bf16tof(ch2.x) + bf16tof(th2.x));
  float p1 = tanhf(bf16tof(ch2.y) + bf16tof(th2.y));
  float v0 = (1.f - z0) * sm0 + z0 * p0;
  float v1 = (1.f - z1) * sm1 + z1 * p1;
  if (m == 0) { v0 = 0.f; v1 = 0.f; }
  short2 h2, l2;
  bf16split(v0, h2.x, l2.x); bf16split(v1, h2.y, l2.y);
  *(short2*)&hP[oP] = h2; *(short2*)&hP[oP + 32] = l2;
}

// Acat packed [n][SPP2]: cols 0-449 = emb, 450-899 = sum h_nei, 900-959 = 0
__global__ void k_nodecat(const float* __restrict__ emb,
                          const int* __restrict__ fnode,
                          const short* __restrict__ hP,
                          const int* __restrict__ ng,
                          short* __restrict__ Apk) {
  int n = blockIdx.x, t = threadIdx.x, j = t * 2;
  if (j < H) {
    float2 v = *(const float2*)&emb[(size_t)fnode[n] * H + j];
    short2 h2, l2;
    bf16split(v.x, h2.x, l2.x); bf16split(v.y, h2.y, l2.y);
    size_t o = ppix(n, j, SPP2);
    *(short2*)&Apk[o] = h2; *(short2*)&Apk[o + 32] = l2;

    const int* e = ng + (size_t)n * KN;
    float s0 = 0.f, s1 = 0.f;
#pragma unroll
    for (int k = 0; k < KN; ++k) {
      size_t oP = ppix(e[k], j, SPP1);
      short2 ph = *(const short2*)&hP[oP];
      short2 pl = *(const short2*)&hP[oP + 32];
      s0 += bf16tof(ph.x) + bf16tof(pl.x);
      s1 += bf16tof(ph.y) + bf16tof(pl.y);
    }
    bf16split(s0, h2.x, l2.x); bf16split(s1, h2.y, l2.y);
    o = ppix(n, 450 + j, SPP2);
    *(short2*)&Apk[o] = h2; *(short2*)&Apk[o + 32] = l2;
  }
  if (t < 30) {   // zero cols [900,960)
    int c = 900 + t * 2;
    short2 z2; z2.x = 0; z2.y = 0;
    size_t o = ppix(n, c, SPP2);
    *(short2*)&Apk[o] = z2; *(short2*)&Apk[o + 32] = z2;
  }
}

// ---------------- launch ----------------

extern "C" void kernel_launch(void* const* d_in, const int* in_sizes, int n_in,
                              void* d_out, int out_size, void* d_ws, size_t ws_size,
                              hipStream_t stream) {
  (void)in_sizes; (void)n_in; (void)out_size; (void)ws_size;

  const int*   fnode      = (const int*)d_in[0];
  const int*   fmess      = (const int*)d_in[1];
  const int*   node_graph = (const int*)d_in[2];
  const int*   mess_graph = (const int*)d_in[3];
  const float* emb        = (const float*)d_in[4];
  const float* Wz         = (const float*)d_in[5];
  const float* bz         = (const float*)d_in[6];
  const float* Wr         = (const float*)d_in[7];
  const float* Ur         = (const float*)d_in[8];
  const float* bu         = (const float*)d_in[9];
  const float* Wh         = (const float*)d_in[10];
  const float* bh         = (const float*)d_in[11];
  const float* Wo         = (const float*)d_in[12];
  const float* bo         = (const float*)d_in[13];

  // ---- workspace: 3 packed planes + CHb + gb + r1b + tzb + thb ≈ 118.7 MB ----
  short* P   = (short*)d_ws;
  short* hP  = P;                     // h packed
  short* shP = P + 1 * PPSZ;          // sum_h packed (later Acat @ SPP2)
  short* ghP = P + 2 * PPSZ;          // sum_gh packed (also fmess_e packed)
  short* CHb = P + 3 * PPSZ;                       // [M][960] bf16: c_z | c_h
  short* gb  = CHb + (size_t)NMESS * LDCH;         // [M][480] bf16: h@Ur
  short* r1b = gb  + (size_t)NMESS * 480;          // [M][480] bf16
  short* tzb = r1b + (size_t)NMESS * 480;          // [M][480] bf16
  short* thb = tzb + (size_t)NMESS * 480;          // [M][480] bf16

  // ---- d_out messages region: packed weights (~8.7 of 18.4 MB) ----
  char*  scr  = (char*)d_out + (size_t)NNODE * H * 4;   // 16B-aligned
  short* BtI  = (short*)scr;                    // [1408][960] packed (WzT|WhT)
  short* BtR  = BtI  + (size_t)1408 * SPP1;     // [512][960] Wr
  short* BtUr = BtR  + (size_t)512 * SPP1;      // [512][960] Ur
  short* BtZ  = BtUr + (size_t)512 * SPP1;      // [512][960] Wz bottom
  short* BtHH = BtZ  + (size_t)512 * SPP1;      // [512][960] Wh bottom
  short* BtO  = BtHH + (size_t)512 * SPP1;      // [512][1920] Wo
  float* biasI = (float*)(BtO + (size_t)512 * SPP2);    // [900]
  int*   idxM  = (int*)(biasI + 912);

  k_build_idx<<<(NMESS + 255) / 256, 256, 0, stream>>>(fnode, fmess, idxM);

  // packed weight prep (fully overwrites every region read later)
  dim3 gT(KP / 32, 16), gT2(KP2 / 32, 16);
  k_wT<<<gT,  256, 0, stream>>>(Wz,                  H, BtI,               KP,  512);
  k_wT<<<gT,  256, 0, stream>>>(Wh,                  H, BtI + 450 * SPP1,  KP,  512);
  k_wT<<<gT,  256, 0, stream>>>(Wr,                  H, BtR,               KP,  512);
  k_wT<<<gT,  256, 0, stream>>>(Ur,                  H, BtUr,              KP,  512);
  k_wT<<<gT,  256, 0, stream>>>(Wz + (size_t)H * H,  H, BtZ,               KP,  512);
  k_wT<<<gT,  256, 0, stream>>>(Wh + (size_t)H * H,  H, BtHH,              KP,  512);
  k_wT<<<gT2, 256, 0, stream>>>(Wo,                 H2, BtO,               KP2, 512);
  k_biascat<<<4, 256, 0, stream>>>(bz, bh, biasI);

  // fmess_e packed into ghP (writes K-tail zeros inline)
  k_embsplit<<<NMESS, 256, 0, stream>>>(emb, idxM, ghP);

  // invariant GEMMs (full 3-product): CHb (c_z|c_h) and r1b
  dim3 gI1(15, MPAD / BM);   // N=900
  gemm4_b<3><<<gI1, 256, 0, stream>>>(ghP, KP, BtI, biasI, CHb, LDCH, NMESS, H2);
  dim3 gI2(8, MPAD / BM);    // N=450
  gemm4_b<3><<<gI2, 256, 0, stream>>>(ghP, KP, BtR, bu, r1b, 480, NMESS, H);

  // step 0 shortcut: h1 = mask * sigmoid(c_z) * tanh(c_h)
  k_h1<<<NMESS, 256, 0, stream>>>(CHb, hP);

  dim3 gB(8, MPAD / BM);     // (8, 162)
  dim3 gP(8, MPAD / BM, 2);  // grouped t_h + t_z
  for (int d = 1; d < 8; ++d) {
    // gb = h @ Ur (bf16, 2-product)
    gemm4_b<2><<<gB, 256, 0, stream>>>(hP, KP, BtUr, nullptr, gb, 480, NMESS, H);
    // sum_h & sum_gh packed in one pass
    k_gather2<<<NMESS, 256, 0, stream>>>(hP, gb, r1b, mess_graph, shP, ghP);
    // thb = ghP@WhB  ||  tzb = shP@WzB   (grouped, 2-product)
    gemm4_pair<<<gP, 256, 0, stream>>>(ghP, BtHH, thb, shP, BtZ, tzb);
    // combine in place -> hP
    k_combine<<<NMESS, 256, 0, stream>>>(CHb, tzb, thb, shP, hP);
  }

  // Acat packed (SPP2) then output GEMM with relu (full 3-product)
  k_nodecat<<<NNODE, 256, 0, stream>>>(emb, fnode, hP, node_graph, shP);
  dim3 gF(8, NNODE / BM);    // (8, 80)
  gemm4<1><<<gF, 256, 0, stream>>>(shP, KP2, BtO, bo, (float*)d_out, H, NNODE, H);

  // messages output = zeros (wipes idx + weights) — AFTER final GEMM
  hipMemsetAsync((float*)d_out + (size_t)NNODE * H, 0, (size_t)NMESS * H * sizeof(float), stream);
}

// Round 17
// 766.804 us; speedup vs baseline: 2.8644x; 1.0551x over previous
//
#include <hip/hip_runtime.h>
#include <cstdint>
#include <cstddef>

#define H 450
#define H2 900
#define KP 480
#define KP2 960
#define NMESS 10241
#define NNODE 5120
#define MPAD 10368                 // 162 * 64
#define SPP1 960                   // packed row stride (shorts) for Kpad=480
#define SPP2 1920                  // for Kpad=960
#define PPSZ ((size_t)MPAD * SPP1) // packed plane size in shorts
#define KM 5
#define KN 6
#define LDCH 1440                  // CHR row stride (bf16): c_z | c_h | r1

typedef __attribute__((ext_vector_type(8))) short short8;   // 8 bf16
typedef __attribute__((ext_vector_type(4))) float f32x4;

__device__ __forceinline__ short bf16rne(float f) {
  union { float f; unsigned u; } x; x.f = f;
  unsigned u = x.u;
  u += 0x7FFF + ((u >> 16) & 1);
  return (short)(u >> 16);
}
__device__ __forceinline__ float bf16tof(short s) {
  union { float f; unsigned u; } x;
  x.u = ((unsigned)(unsigned short)s) << 16;
  return x.f;
}
__device__ __forceinline__ void bf16split(float v, short& hi, short& lo) {
  hi = bf16rne(v);
  lo = bf16rne(v - bf16tof(hi));
}
__device__ __forceinline__ float sigmoidf_(float x) {
  return 1.f / (1.f + __expf(-x));
}

// packed element offset: hi at PPIX, lo at PPIX+32
__device__ __forceinline__ size_t ppix(int row, int k, int spp) {
  return (size_t)row * spp + ((k >> 5) << 6) + (k & 31);
}

// direct global->LDS 16B DMA (LDS dest: wave-uniform base + lane*16)
__device__ __forceinline__ void gll16(const short* g, short* l) {
  __builtin_amdgcn_global_load_lds(
      (const __attribute__((address_space(1))) void*)g,
      (__attribute__((address_space(3))) void*)l, 16, 0, 0);
}

// ---------------- split-bf16 MFMA GEMM: packed planes (r11-proven core) ----
// A,B packed [row][k-chunk][hi*32|lo*32] bf16. 256 thr (4 waves, 32x32 wave
// tiles), BK=32, 2-buf 32 KB LDS -> 5 blocks/CU. gload_lds staging: one
// contiguous 128B run per row per chunk; source slot = (lane&7)^(row&7),
// read-side XOR matches. XCD-chunked block swizzle.
// PROD: 3 = full split (Ahi*Bhi + Alo*Bhi + Ahi*Blo), 2 = drop Ahi*Blo.
#define BM 64
#define BN 64
#define BK 32

struct SmemT { short As[2][64][64]; short Bs[2][64][64]; };   // 32 KB

__device__ __forceinline__ void xcd_swz(int gx, int gy, int& bm, int& bn) {
  const int nwg = gx * gy;
  int lid = blockIdx.y * gx + blockIdx.x;
  const int q = nwg >> 3, r = nwg & 7;
  const int xcd = lid & 7, seq = lid >> 3;
  int sid = (xcd < r) ? (xcd * (q + 1) + seq)
                      : (r * (q + 1) + (xcd - r) * q + seq);
  bm = (sid / gx) * BM;
  bn = (sid % gx) * BN;
}

// OUT: 0 = f32 C (+bias, opt relu)
//      3 = single bf16 (Cs, stride ldc), +bias
template<int ACT, int OUT, int PROD>
__device__ __forceinline__ void gemm_core(
    SmemT& sm, const short* __restrict__ Apk, int Kpad,
    const short* __restrict__ Bpk,
    const float* __restrict__ bias,
    float* C, int ldc, short* Cs,
    int M, int N, int bm, int bn)
{
  const int tid  = threadIdx.x;
  const int lane = tid & 63;
  const int wid  = tid >> 6;          // 0..3
  const int wm   = (wid >> 1) * 32;
  const int wn   = (wid & 1) * 32;
  const int l15  = lane & 15;
  const int s8   = (lane >> 4) * 8;   // k sub-offset in halves
  const int rr0  = (lane >> 4) * 4;
  const int spp  = Kpad * 2;

  // staging: unified 128 rows (0-63 = A, 64-127 = B); wave wid -> rows 32w..32w+31
  const int lr = lane >> 3;
  const int sl = lane & 7;
  const int t0 = sl ^ lr;             // packed slot (0-3 hi, 4-7 lo)
  const short* src[4];
#pragma unroll
  for (int qq = 0; qq < 4; ++qq) {
    const int rrow = wid * 32 + qq * 8 + lr;
    const bool isA = rrow < 64;
    const int grow = isA ? (bm + rrow) : (bn + rrow - 64);
    src[qq] = (isA ? Apk : Bpk) + (size_t)grow * spp + t0 * 8;
  }
  const int nk = Kpad / BK;

  f32x4 acc[2][2];
#pragma unroll
  for (int i = 0; i < 2; ++i)
#pragma unroll
    for (int j = 0; j < 2; ++j)
#pragma unroll
      for (int t = 0; t < 4; ++t) acc[i][j][t] = 0.f;

  auto STAGE = [&](int b, int koff) {
#pragma unroll
    for (int qq = 0; qq < 4; ++qq) {
      const int r0 = wid * 32 + qq * 8;
      short* d = (r0 < 64) ? &sm.As[b][r0][0] : &sm.Bs[b][r0 - 64][0];
      gll16(src[qq] + koff, d);
    }
  };

  STAGE(0, 0);
  __syncthreads();
  int cur = 0;
  for (int t = 0; t < nk; ++t) {
    if (t + 1 < nk) STAGE(cur ^ 1, (t + 1) * 64);
    short8 ah[2], al[2], bh[2], bl[2];
#pragma unroll
    for (int i = 0; i < 2; ++i) {
      const int rA = wm + i*16 + l15;
      const int xr = (rA & 7) << 3;
      ah[i] = *(const short8*)&sm.As[cur][rA][(s8)      ^ xr];
      al[i] = *(const short8*)&sm.As[cur][rA][(s8 + 32) ^ xr];
    }
#pragma unroll
    for (int j = 0; j < 2; ++j) {
      const int rB = wn + j*16 + l15;
      const int xr = (rB & 7) << 3;
      bh[j] = *(const short8*)&sm.Bs[cur][rB][(s8)      ^ xr];
      if (PROD == 3)
        bl[j] = *(const short8*)&sm.Bs[cur][rB][(s8 + 32) ^ xr];
    }
    __builtin_amdgcn_s_setprio(1);
#pragma unroll
    for (int j = 0; j < 2; ++j)
#pragma unroll
      for (int i = 0; i < 2; ++i) {
        acc[i][j] = __builtin_amdgcn_mfma_f32_16x16x32_bf16(ah[i], bh[j], acc[i][j], 0, 0, 0);
        acc[i][j] = __builtin_amdgcn_mfma_f32_16x16x32_bf16(al[i], bh[j], acc[i][j], 0, 0, 0);
        if (PROD == 3)
          acc[i][j] = __builtin_amdgcn_mfma_f32_16x16x32_bf16(ah[i], bl[j], acc[i][j], 0, 0, 0);
      }
    __builtin_amdgcn_s_setprio(0);
    __syncthreads();   // drains next-tile gload_lds + read/write order
    cur ^= 1;
  }

#pragma unroll
  for (int j = 0; j < 2; ++j) {
    int col = bn + wn + j*16 + l15;
    if (col >= N) continue;
    float bv = bias ? bias[col] : 0.f;
#pragma unroll
    for (int i = 0; i < 2; ++i) {
      int row0 = bm + wm + i*16 + rr0;
#pragma unroll
      for (int rr = 0; rr < 4; ++rr) {
        int row = row0 + rr;
        if (row >= M) continue;
        float v = acc[i][j][rr] + bv;
        if (OUT == 0) {
          if (ACT == 1) v = fmaxf(v, 0.f);
          C[(size_t)row * ldc + col] = v;
        } else {  // OUT == 3: single bf16, stride ldc
          Cs[(size_t)row * ldc + col] = bf16rne(v);
        }
      }
    }
  }
}

template<int ACT>
__global__ __launch_bounds__(256, 5)
void gemm4(const short* __restrict__ Apk, int Kpad,
           const short* __restrict__ Bpk,
           const float* __restrict__ bias,
           float* C, int ldc, int M, int N)
{
  __shared__ SmemT sm;
  int bm, bn; xcd_swz(gridDim.x, gridDim.y, bm, bn);
  gemm_core<ACT, 0, 3>(sm, Apk, Kpad, Bpk, bias, C, ldc, nullptr, M, N, bm, bn);
}

// single-bf16 output GEMM; PROD = split products (3 = invariants, 2 = gates)
template<int PROD>
__global__ __launch_bounds__(256, 5)
void gemm4_b(const short* __restrict__ Apk, int Kpad,
             const short* __restrict__ Bpk,
             const float* __restrict__ bias,
             short* Cs, int ldcs, int M, int N)
{
  __shared__ SmemT sm;
  int bm, bn; xcd_swz(gridDim.x, gridDim.y, bm, bn);
  gemm_core<0, 3, PROD>(sm, Apk, Kpad, Bpk, bias, nullptr, ldcs, Cs, M, N, bm, bn);
}

// grouped pair: z=0: thb = ghP@WhB ; z=1: tzb = shP@WzB   (both bf16 [M][480])
__global__ __launch_bounds__(256, 5)
void gemm4_pair(const short* __restrict__ A0, const short* __restrict__ B0,
                short* C0,
                const short* __restrict__ A1, const short* __restrict__ B1,
                short* C1)
{
  __shared__ SmemT sm;
  int bm, bn; xcd_swz(gridDim.x, gridDim.y, bm, bn);
  if (blockIdx.z == 0)
    gemm_core<0, 3, 2>(sm, A0, KP, B0, nullptr, nullptr, 480, C0, NMESS, H, bm, bn);
  else
    gemm_core<0, 3, 2>(sm, A1, KP, B1, nullptr, nullptr, 480, C1, NMESS, H, bm, bn);
}

// ---------------- merged weight prep: z selects matrix; z=7 = bias concat ----
// Writes rows c < 450 only; rows >= 450 feed only discarded output cols.
__device__ __forceinline__ void wT_one(const float* __restrict__ W, int Kreal,
                                       short* __restrict__ Bt, int Kpad) {
  __shared__ float T[32][33];
  const int tx = threadIdx.x & 31;
  const int ty = threadIdx.x >> 5;
  const int k0 = blockIdx.x * 32;
  const int c0 = blockIdx.y * 32;
  const int spp = Kpad * 2;
  if (k0 >= Kpad) return;
#pragma unroll
  for (int i = 0; i < 4; ++i) {
    int k = k0 + ty + i*8, c = c0 + tx;
    T[ty + i*8][tx] = (k < Kreal && c < H) ? W[(size_t)k * H + c] : 0.f;
  }
  __syncthreads();
#pragma unroll
  for (int i = 0; i < 4; ++i) {
    int c = c0 + ty + i*8, k = k0 + tx;
    if (k < Kpad && c < H) {
      short hi, lo;
      bf16split(T[tx][ty + i*8], hi, lo);
      size_t o = ppix(c, k, spp);
      Bt[o] = hi; Bt[o + 32] = lo;
    }
  }
}

__global__ __launch_bounds__(256)
void k_wprep(const float* __restrict__ Wz, const float* __restrict__ Wh,
             const float* __restrict__ Wr, const float* __restrict__ Ur,
             const float* __restrict__ Wo,
             const float* __restrict__ bz, const float* __restrict__ bh,
             const float* __restrict__ bu,
             short* BtIR, short* BtUr, short* BtZ, short* BtHH, short* BtO,
             float* biasI)
{
  const int z = blockIdx.z;
  switch (z) {
    case 0: wT_one(Wz,                  H,  BtIR,              KP);  break;
    case 1: wT_one(Wh,                  H,  BtIR + 450 * SPP1, KP);  break;
    case 2: wT_one(Wr,                  H,  BtIR + 900 * SPP1, KP);  break;
    case 3: wT_one(Ur,                  H,  BtUr,              KP);  break;
    case 4: wT_one(Wz + (size_t)H * H,  H,  BtZ,               KP);  break;
    case 5: wT_one(Wh + (size_t)H * H,  H,  BtHH,              KP);  break;
    case 6: wT_one(Wo,                  H2, BtO,               KP2); break;
    default: {  // z = 7: biasI[1350] = bz | bh | bu
      if (blockIdx.x == 0 && blockIdx.y < 6) {
        int c = blockIdx.y * 256 + threadIdx.x;
        if (c < 1350) {
          float v;
          if (c < 450)      v = bz[c];
          else if (c < 900) v = bh[c - 450];
          else              v = bu[c - 900];
          biasI[c] = v;
        }
      }
      break;
    }
  }
}

// ---------------- elementwise / gather kernels ----------------

// fmess_e packed (idx computed inline: emb[fnode[fmess[m]]])
__global__ void k_embsplit(const float* __restrict__ emb,
                           const int* __restrict__ fnode,
                           const int* __restrict__ fmess,
                           short* __restrict__ eP) {
  int m = blockIdx.x, j = threadIdx.x * 2;
  if (j >= KP) return;
  size_t o = ppix(m, j, SPP1);
  if (j < H) {
    int row = fnode[fmess[m]];
    float2 v = *(const float2*)&emb[(size_t)row * H + j];
    short2 h2, l2;
    bf16split(v.x, h2.x, l2.x); bf16split(v.y, h2.y, l2.y);
    *(short2*)&eP[o] = h2; *(short2*)&eP[o + 32] = l2;
  } else {                      // K-tail cols [450,480) must be 0
    short2 z2; z2.x = 0; z2.y = 0;
    *(short2*)&eP[o] = z2; *(short2*)&eP[o + 32] = z2;
  }
}

// step 0: h1 = mask * sigmoid(c_z) * tanh(c_h)   (sum_h = t_z = t_h = 0)
__global__ void k_h1(const short* __restrict__ CHR, short* __restrict__ hP) {
  int m = blockIdx.x, j = threadIdx.x * 2;
  if (j >= KP) return;
  size_t oP = ppix(m, j, SPP1);
  if (j < H) {
    size_t oc = (size_t)m * LDCH + j;
    short2 cz2 = *(const short2*)&CHR[oc];
    short2 ch2 = *(const short2*)&CHR[oc + 450];
    float v0 = sigmoidf_(bf16tof(cz2.x)) * tanhf(bf16tof(ch2.x));
    float v1 = sigmoidf_(bf16tof(cz2.y)) * tanhf(bf16tof(ch2.y));
    if (m == 0) { v0 = 0.f; v1 = 0.f; }
    short2 h2, l2;
    bf16split(v0, h2.x, l2.x); bf16split(v1, h2.y, l2.y);
    *(short2*)&hP[oP] = h2; *(short2*)&hP[oP + 32] = l2;
  } else {
    short2 z2; z2.x = 0; z2.y = 0;
    *(short2*)&hP[oP] = z2; *(short2*)&hP[oP + 32] = z2;
  }
}

// one pass over neighbors: sum_h (packed) + sum_gh (packed)
// gb = h@Ur, bf16 [M][480]; r1 at CHR col 900
__global__ void k_gather2(const short* __restrict__ hP,
                          const short* __restrict__ gb,
                          const short* __restrict__ CHR,
                          const int* __restrict__ mg,
                          short* __restrict__ shP, short* __restrict__ ghP) {
  int m = blockIdx.x, j = threadIdx.x * 2;
  if (j >= KP) return;
  size_t o = ppix(m, j, SPP1);
  if (j >= H) {                 // K-tail zeros
    short2 z2; z2.x = 0; z2.y = 0;
    *(short2*)&shP[o] = z2; *(short2*)&shP[o + 32] = z2;
    *(short2*)&ghP[o] = z2; *(short2*)&ghP[o + 32] = z2;
    return;
  }
  const int* e = mg + (size_t)m * KM;
  short2 rb2 = *(const short2*)&CHR[(size_t)m * LDCH + 900 + j];
  float rb0 = bf16tof(rb2.x), rb1 = bf16tof(rb2.y);
  float s0 = 0.f, s1 = 0.f, t0 = 0.f, t1 = 0.f;
#pragma unroll
  for (int k = 0; k < KM; ++k) {
    int ek = e[k];
    size_t oP = ppix(ek, j, SPP1);
    short2 gv = *(const short2*)&gb[(size_t)ek * 480 + j];
    short2 ph = *(const short2*)&hP[oP];
    short2 pl = *(const short2*)&hP[oP + 32];
    float h0 = bf16tof(ph.x) + bf16tof(pl.x);
    float h1 = bf16tof(ph.y) + bf16tof(pl.y);
    s0 += h0;                                  s1 += h1;
    t0 += sigmoidf_(rb0 + bf16tof(gv.x)) * h0; t1 += sigmoidf_(rb1 + bf16tof(gv.y)) * h1;
  }
  short2 h2, l2;
  bf16split(s0, h2.x, l2.x); bf16split(s1, h2.y, l2.y);
  *(short2*)&shP[o] = h2; *(short2*)&shP[o + 32] = l2;
  bf16split(t0, h2.x, l2.x); bf16split(t1, h2.y, l2.y);
  *(short2*)&ghP[o] = h2; *(short2*)&ghP[o + 32] = l2;
}

// h = mask*((1-z)*sum_h + z*tanh(c_h+t_h)); coalesced, in place on hP
__global__ void k_combine(const short* __restrict__ CHR,   // [M][1440] bf16
                          const short* __restrict__ tzb,   // [M][480] bf16
                          const short* __restrict__ thb,   // [M][480] bf16
                          const short* __restrict__ shP,
                          short* hP) {
  int m = blockIdx.x, j = threadIdx.x * 2;
  if (j >= H) return;           // K-tail of hP stays zero
  size_t oc = (size_t)m * LDCH + j;
  size_t oP = ppix(m, j, SPP1);
  short2 cz2 = *(const short2*)&CHR[oc];
  short2 ch2 = *(const short2*)&CHR[oc + 450];
  short2 tz2 = *(const short2*)&tzb[(size_t)m * 480 + j];
  short2 th2 = *(const short2*)&thb[(size_t)m * 480 + j];
  short2 smh = *(const short2*)&shP[oP];
  short2 sml = *(const short2*)&shP[oP + 32];
  float sm0 = bf16tof(smh.x) + bf16tof(sml.x);
  float sm1 = bf16tof(smh.y) + bf16tof(sml.y);
  float z0 = sigmoidf_(bf16tof(cz2.x) + bf16tof(tz2.x));
  float z1 = sigmoidf_(bf16tof(cz2.y) + bf16tof(tz2.y));
  float p0 = tanhf(bf16tof(ch2.x) + bf16tof(th2.x));
  float p1 = tanhf(bf16tof(ch2.y) + bf16tof(th2.y));
  float v0 = (1.f - z0) * sm0 + z0 * p0;
  float v1 = (1.f - z1) * sm1 + z1 * p1;
  if (m == 0) { v0 = 0.f; v1 = 0.f; }
  short2 h2, l2;
  bf16split(v0, h2.x, l2.x); bf16split(v1, h2.y, l2.y);
  *(short2*)&hP[oP] = h2; *(short2*)&hP[oP + 32] = l2;
}

// Acat packed [n][SPP2]: cols 0-449 = emb, 450-899 = sum h_nei, 900-959 = 0
__global__ void k_nodecat(const float* __restrict__ emb,
                          const int* __restrict__ fnode,
                          const short* __restrict__ hP,
                          const int* __restrict__ ng,
                          short* __restrict__ Apk) {
  int n = blockIdx.x, t = threadIdx.x, j = t * 2;
  if (j < H) {
    float2 v = *(const float2*)&emb[(size_t)fnode[n] * H + j];
    short2 h2, l2;
    bf16split(v.x, h2.x, l2.x); bf16split(v.y, h2.y, l2.y);
    size_t o = ppix(n, j, SPP2);
    *(short2*)&Apk[o] = h2; *(short2*)&Apk[o + 32] = l2;

    const int* e = ng + (size_t)n * KN;
    float s0 = 0.f, s1 = 0.f;
#pragma unroll
    for (int k = 0; k < KN; ++k) {
      size_t oP = ppix(e[k], j, SPP1);
      short2 ph = *(const short2*)&hP[oP];
      short2 pl = *(const short2*)&hP[oP + 32];
      s0 += bf16tof(ph.x) + bf16tof(pl.x);
      s1 += bf16tof(ph.y) + bf16tof(pl.y);
    }
    bf16split(s0, h2.x, l2.x); bf16split(s1, h2.y, l2.y);
    o = ppix(n, 450 + j, SPP2);
    *(short2*)&Apk[o] = h2; *(short2*)&Apk[o + 32] = l2;
  }
  if (t < 30) {   // zero cols [900,960)
    int c = 900 + t * 2;
    short2 z2; z2.x = 0; z2.y = 0;
    size_t o = ppix(n, c, SPP2);
    *(short2*)&Apk[o] = z2; *(short2*)&Apk[o + 32] = z2;
  }
}

// ---------------- launch ----------------

extern "C" void kernel_launch(void* const* d_in, const int* in_sizes, int n_in,
                              void* d_out, int out_size, void* d_ws, size_t ws_size,
                              hipStream_t stream) {
  (void)in_sizes; (void)n_in; (void)out_size; (void)ws_size;

  const int*   fnode      = (const int*)d_in[0];
  const int*   fmess      = (const int*)d_in[1];
  const int*   node_graph = (const int*)d_in[2];
  const int*   mess_graph = (const int*)d_in[3];
  const float* emb        = (const float*)d_in[4];
  const float* Wz         = (const float*)d_in[5];
  const float* bz         = (const float*)d_in[6];
  const float* Wr         = (const float*)d_in[7];
  const float* Ur         = (const float*)d_in[8];
  const float* bu         = (const float*)d_in[9];
  const float* Wh         = (const float*)d_in[10];
  const float* bh         = (const float*)d_in[11];
  const float* Wo         = (const float*)d_in[12];
  const float* bo         = (const float*)d_in[13];

  // ---- workspace: 3 packed planes + CHR + gb + tzb + thb ≈ 118.7 MB ----
  short* P   = (short*)d_ws;
  short* hP  = P;                     // h packed
  short* shP = P + 1 * PPSZ;          // sum_h packed (later Acat @ SPP2)
  short* ghP = P + 2 * PPSZ;          // sum_gh packed (also fmess_e packed)
  short* CHR = P + 3 * PPSZ;                       // [M][1440] bf16: c_z|c_h|r1
  short* gb  = CHR + (size_t)NMESS * LDCH;         // [M][480] bf16: h@Ur
  short* tzb = gb  + (size_t)NMESS * 480;          // [M][480] bf16
  short* thb = tzb + (size_t)NMESS * 480;          // [M][480] bf16

  // ---- d_out messages region: packed weights (~7.6 of 18.4 MB) ----
  char*  scr  = (char*)d_out + (size_t)NNODE * H * 4;   // 16B-aligned
  short* BtIR = (short*)scr;                    // [1408][960]: WzT|WhT|Wr rows 0/450/900
  short* BtUr = BtIR + (size_t)1408 * SPP1;     // [512][960] Ur
  short* BtZ  = BtUr + (size_t)512 * SPP1;      // [512][960] Wz bottom
  short* BtHH = BtZ  + (size_t)512 * SPP1;      // [512][960] Wh bottom
  short* BtO  = BtHH + (size_t)512 * SPP1;      // [512][1920] Wo
  float* biasI = (float*)(BtO + (size_t)512 * SPP2);    // [1350]

  // merged weight prep: 7 transposes + bias concat in one dispatch
  dim3 gW(KP2 / 32, 16, 8);   // (30, 16, 8); z<6 blocks with bx>=15 early-out
  k_wprep<<<gW, 256, 0, stream>>>(Wz, Wh, Wr, Ur, Wo, bz, bh, bu,
                                  BtIR, BtUr, BtZ, BtHH, BtO, biasI);

  // fmess_e packed into ghP (inline idx; K-tail zeros inline)
  k_embsplit<<<NMESS, 256, 0, stream>>>(emb, fnode, fmess, ghP);

  // merged invariant GEMM (full 3-product): CHR = fmess_e @ [WzT|WhT|Wr] + [bz|bh|bu]
  dim3 gI(22, MPAD / BM);    // N=1350
  gemm4_b<3><<<gI, 256, 0, stream>>>(ghP, KP, BtIR, biasI, CHR, LDCH, NMESS, 1350);

  // step 0 shortcut: h1 = mask * sigmoid(c_z) * tanh(c_h)
  k_h1<<<NMESS, 256, 0, stream>>>(CHR, hP);

  dim3 gB(8, MPAD / BM);     // (8, 162)
  dim3 gP(8, MPAD / BM, 2);  // grouped t_h + t_z
  for (int d = 1; d < 8; ++d) {
    // gb = h @ Ur (bf16, 2-product)
    gemm4_b<2><<<gB, 256, 0, stream>>>(hP, KP, BtUr, nullptr, gb, 480, NMESS, H);
    // sum_h & sum_gh packed in one pass
    k_gather2<<<NMESS, 256, 0, stream>>>(hP, gb, CHR, mess_graph, shP, ghP);
    // thb = ghP@WhB  ||  tzb = shP@WzB   (grouped, 2-product)
    gemm4_pair<<<gP, 256, 0, stream>>>(ghP, BtHH, thb, shP, BtZ, tzb);
    // combine in place -> hP
    k_combine<<<NMESS, 256, 0, stream>>>(CHR, tzb, thb, shP, hP);
  }

  // Acat packed (SPP2) then output GEMM with relu (full 3-product)
  k_nodecat<<<NNODE, 256, 0, stream>>>(emb, fnode, hP, node_graph, shP);
  dim3 gF(8, NNODE / BM);    // (8, 80)
  gemm4<1><<<gF, 256, 0, stream>>>(shP, KP2, BtO, bo, (float*)d_out, H, NNODE, H);

  // messages output = zeros (wipes weight scratch) — AFTER final GEMM
  hipMemsetAsync((float*)d_out + (size_t)NNODE * H, 0, (size_t)NMESS * H * sizeof(float), stream);
}